// Round 5
// baseline (8868.581 us; speedup 1.0000x reference)
//
#include <hip/hip_runtime.h>
#include <hip/hip_cooperative_groups.h>
#include <math.h>

namespace cg = cooperative_groups;

typedef unsigned short u16;
typedef unsigned int u32;
typedef __bf16 bf16x8 __attribute__((ext_vector_type(8)));
typedef float floatx4 __attribute__((ext_vector_type(4)));

#define MFMA16(a, b, c) __builtin_amdgcn_mfma_f32_16x16x32_bf16((a), (b), (c), 0, 0, 0)

__device__ __forceinline__ float bf2f(u16 u) {
  u32 x = ((u32)u) << 16; float f; __builtin_memcpy(&f, &x, 4); return f;
}
__device__ __forceinline__ u16 f2bf(float f) {
  u32 x; __builtin_memcpy(&x, &f, 4);
  return (u16)((x + 0x7FFFu + ((x >> 16) & 1u)) >> 16);  // RNE
}
__device__ __forceinline__ void store_dual(u16* outp, float v) {
  u32 h = (u32)f2bf(v);
  *(u32*)outp = (h << 16) | h;
}
__device__ __forceinline__ bf16x8 ld8(const u16* p) { return *(const bf16x8*)p; }

__device__ __forceinline__ float wred64(float v) {
#pragma unroll
  for (int off = 32; off > 0; off >>= 1) v += __shfl_down(v, off, 64);
  return v;
}

// flag-aware final store: f32 output (flag=1, observed) or bf16 (flag=0)
__device__ __forceinline__ void store_final(u16* outp, float ev, int flag) {
  if (!(ev == ev) || fabsf(ev) > 1e37f) ev = -12345.0f - 1000.0f * (float)flag;
  if (flag) *(float*)outp = ev;
  else outp[0] = f2bf(ev);
}

// ---------------- diagnostics ----------------
__global__ void k_sentinel(u16* outp, float v) {
  if (threadIdx.x == 0 && blockIdx.x == 0) store_dual(outp, v);
}

// ---------------- input dtype detect: flag=1 if f32, 0 if bf16 ----------------
__global__ void k_detect(const u32* __restrict__ raw, int* __restrict__ flag) {
  if (threadIdx.x == 0 && blockIdx.x == 0) {
    int outliers = 0;
    for (int i = 0; i < 64; ++i) {
      u32 lo = raw[i] & 0xFFFFu;
      int e = (int)((lo >> 7) & 0xFF);
      if (e < 100 || e > 150) ++outliers;
    }
    *flag = (outliers > 16) ? 1 : 0;
  }
}

// ---------------- dtype-aware convert-to-bf16 ----------------
__global__ void k_cvt(const float* __restrict__ inf_, const u16* __restrict__ inb,
                      u16* __restrict__ out, int n, const int* __restrict__ flag) {
  int i = blockIdx.x * 256 + threadIdx.x;
  if (i >= n) return;
  out[i] = (*flag) ? f2bf(inf_[i]) : inb[i];
}

// ---------------- transpose (bf16), out[c][r] = in[r][c] ----------------
__global__ void k_transpose(const u16* __restrict__ in, u16* __restrict__ out, int R, int C) {
  int i = blockIdx.x * 256 + threadIdx.x;
  if (i < R * C) { int r = i / C, c = i - r * C; out[c * R + r] = in[i]; }
}

// ---------------- start-vector MLP (1 block) -> ex0[128] ----------------
__global__ __launch_bounds__(256) void k_start(
    const u16* __restrict__ se,
    const u16* __restrict__ sw0, const u16* __restrict__ sb0,
    const u16* __restrict__ sw1, const u16* __restrict__ sb1,
    const u16* __restrict__ sw2, const u16* __restrict__ sb2,
    const u16* __restrict__ sw3, const u16* __restrict__ sb3,
    const u16* __restrict__ sw4, const u16* __restrict__ sb4,
    const u16* __restrict__ proj, float* __restrict__ ex0) {
  __shared__ float xa[256], xb[256], xc[256], red[256];
  const int tid = threadIdx.x;
  xa[tid] = bf2f(se[tid]);
  __syncthreads();
  float acc = bf2f(sb0[tid]);
  for (int k = 0; k < 256; ++k) acc += xa[k] * bf2f(sw0[k * 256 + tid]);
  xb[tid] = acc;  // f0 (Linear, no relu)
  __syncthreads();
  acc = bf2f(sb1[tid]);
  for (int k = 0; k < 256; ++k) acc += xb[k] * bf2f(sw1[k * 256 + tid]);
  xc[tid] = fmaxf(acc, 0.f);
  __syncthreads();
  acc = bf2f(sb2[tid]);
  for (int k = 0; k < 256; ++k) acc += xc[k] * bf2f(sw2[k * 256 + tid]);
  xa[tid] = fmaxf(acc, 0.f) + xb[tid];  // f1
  __syncthreads();
  acc = bf2f(sb3[tid]);
  for (int k = 0; k < 256; ++k) acc += xa[k] * bf2f(sw3[k * 256 + tid]);
  xc[tid] = fmaxf(acc, 0.f);
  __syncthreads();
  acc = bf2f(sb4[tid]);
  for (int k = 0; k < 256; ++k) acc += xc[k] * bf2f(sw4[k * 256 + tid]);
  xb[tid] = fmaxf(acc, 0.f) + xa[tid];  // f2
  __syncthreads();
  red[tid] = xb[tid] * xb[tid];
  __syncthreads();
  for (int s = 128; s > 0; s >>= 1) {
    if (tid < s) red[tid] += red[tid + s];
    __syncthreads();
  }
  const float rs = rsqrtf(red[0]);
  xa[tid] = xb[tid] * rs;
  __syncthreads();
  if (tid < 128) {
    float a = 0.f;
    for (int k = 0; k < 256; ++k) a += xa[k] * bf2f(proj[k * 128 + tid]);
    ex0[tid] = expf(a);
  }
}

// ---------------- preterminal MLP: ft = res(res(X0)) via MFMA ----------------
__global__ __launch_bounds__(256) void k_mlp(
    const u16* __restrict__ X0,
    const u16* __restrict__ w1T, const u16* __restrict__ b1,
    const u16* __restrict__ w2T, const u16* __restrict__ b2,
    const u16* __restrict__ w3T, const u16* __restrict__ b3,
    const u16* __restrict__ w4T, const u16* __restrict__ b4,
    u16* __restrict__ FT) {
  __shared__ __align__(16) u16 Y[2][64][264];
  const int tid = threadIdx.x, lane = tid & 63, w = tid >> 6;
  const int m16 = lane & 15, kg = lane >> 4;
  const int rbl = w * 16;
  const int rbg = blockIdx.x * 64 + rbl;
  const floatx4 z4 = {0.f, 0.f, 0.f, 0.f};
  floatx4 acc[16];

#pragma unroll
  for (int ct = 0; ct < 16; ++ct) acc[ct] = z4;
  for (int k0 = 0; k0 < 256; k0 += 32) {
    bf16x8 a = ld8(X0 + (size_t)(rbg + m16) * 256 + k0 + kg * 8);
#pragma unroll
    for (int ct = 0; ct < 16; ++ct)
      acc[ct] = MFMA16(a, ld8(w1T + (ct * 16 + m16) * 256 + k0 + kg * 8), acc[ct]);
  }
#pragma unroll
  for (int ct = 0; ct < 16; ++ct) {
    const int col = ct * 16 + m16;
    const float bv = bf2f(b1[col]);
#pragma unroll
    for (int r = 0; r < 4; ++r)
      Y[0][rbl + kg * 4 + r][col] = f2bf(fmaxf(acc[ct][r] + bv, 0.f));
  }
  __syncthreads();
#pragma unroll
  for (int ct = 0; ct < 16; ++ct) acc[ct] = z4;
  for (int k0 = 0; k0 < 256; k0 += 32) {
    bf16x8 a = *(const bf16x8*)(&Y[0][rbl + m16][k0 + kg * 8]);
#pragma unroll
    for (int ct = 0; ct < 16; ++ct)
      acc[ct] = MFMA16(a, ld8(w2T + (ct * 16 + m16) * 256 + k0 + kg * 8), acc[ct]);
  }
#pragma unroll
  for (int ct = 0; ct < 16; ++ct) {
    const int col = ct * 16 + m16;
    const float bv = bf2f(b2[col]);
#pragma unroll
    for (int r = 0; r < 4; ++r) {
      const int gr = rbg + kg * 4 + r;
      float v = fmaxf(acc[ct][r] + bv, 0.f) + bf2f(X0[(size_t)gr * 256 + col]);
      Y[1][rbl + kg * 4 + r][col] = f2bf(v);
    }
  }
  __syncthreads();
#pragma unroll
  for (int ct = 0; ct < 16; ++ct) acc[ct] = z4;
  for (int k0 = 0; k0 < 256; k0 += 32) {
    bf16x8 a = *(const bf16x8*)(&Y[1][rbl + m16][k0 + kg * 8]);
#pragma unroll
    for (int ct = 0; ct < 16; ++ct)
      acc[ct] = MFMA16(a, ld8(w3T + (ct * 16 + m16) * 256 + k0 + kg * 8), acc[ct]);
  }
#pragma unroll
  for (int ct = 0; ct < 16; ++ct) {
    const int col = ct * 16 + m16;
    const float bv = bf2f(b3[col]);
#pragma unroll
    for (int r = 0; r < 4; ++r)
      Y[0][rbl + kg * 4 + r][col] = f2bf(fmaxf(acc[ct][r] + bv, 0.f));
  }
  __syncthreads();
#pragma unroll
  for (int ct = 0; ct < 16; ++ct) acc[ct] = z4;
  for (int k0 = 0; k0 < 256; k0 += 32) {
    bf16x8 a = *(const bf16x8*)(&Y[0][rbl + m16][k0 + kg * 8]);
#pragma unroll
    for (int ct = 0; ct < 16; ++ct)
      acc[ct] = MFMA16(a, ld8(w4T + (ct * 16 + m16) * 256 + k0 + kg * 8), acc[ct]);
  }
#pragma unroll
  for (int ct = 0; ct < 16; ++ct) {
    const int col = ct * 16 + m16;
    const float bv = bf2f(b4[col]);
#pragma unroll
    for (int r = 0; r < 4; ++r) {
      const int rl = rbl + kg * 4 + r;
      float v = fmaxf(acc[ct][r] + bv, 0.f) + bf2f(Y[1][rl][col]);
      FT[(size_t)(rbg + kg * 4 + r) * 256 + col] = f2bf(v);
    }
  }
}

// ---------------- per-row 1/||x|| over 256 cols ----------------
__global__ __launch_bounds__(256) void k_rownorm(const u16* __restrict__ X,
                                                 float* __restrict__ rscale, int rows) {
  const int w = threadIdx.x >> 6, lane = threadIdx.x & 63;
  const int row = blockIdx.x * 4 + w;
  if (row >= rows) return;
  const u16* p = X + (size_t)row * 256 + lane * 4;
  float s = 0.f;
#pragma unroll
  for (int i = 0; i < 4; ++i) { float v = bf2f(p[i]); s += v * v; }
  s = wred64(s);
  if (lane == 0) rscale[row] = rsqrtf(s);
}

// ---------------- features: OUT[r][d] = exp(rscale[r] * X[r]·projT[d]) ----------------
__global__ __launch_bounds__(256) void k_feat(const u16* __restrict__ X,
                                              const float* __restrict__ rscale,
                                              const u16* __restrict__ PT,
                                              u16* __restrict__ OUT) {
  const int tid = threadIdx.x, lane = tid & 63, w = tid >> 6;
  const int m16 = lane & 15, kg = lane >> 4;
  const int rb = blockIdx.x * 64 + w * 16;
  const floatx4 z4 = {0.f, 0.f, 0.f, 0.f};
  floatx4 acc[8];
#pragma unroll
  for (int ct = 0; ct < 8; ++ct) acc[ct] = z4;
  for (int k0 = 0; k0 < 256; k0 += 32) {
    bf16x8 a = ld8(X + (size_t)(rb + m16) * 256 + k0 + kg * 8);
#pragma unroll
    for (int ct = 0; ct < 8; ++ct)
      acc[ct] = MFMA16(a, ld8(PT + (ct * 16 + m16) * 256 + k0 + kg * 8), acc[ct]);
  }
  float rs[4];
#pragma unroll
  for (int r = 0; r < 4; ++r) rs[r] = rscale[rb + kg * 4 + r];
#pragma unroll
  for (int ct = 0; ct < 8; ++ct)
#pragma unroll
    for (int r = 0; r < 4; ++r)
      OUT[(size_t)(rb + kg * 4 + r) * 128 + ct * 16 + m16] = f2bf(expf(acc[ct][r] * rs[r]));
}

// ---------------- term features fused with column-sum ----------------
__global__ __launch_bounds__(256) void k_feat_colsum(const u16* __restrict__ X,
                                                     const float* __restrict__ rscale,
                                                     const u16* __restrict__ PT,
                                                     float* __restrict__ part) {
  __shared__ float cred[128];
  const int tid = threadIdx.x, lane = tid & 63, w = tid >> 6;
  const int m16 = lane & 15, kg = lane >> 4;
  const int rb = blockIdx.x * 64 + w * 16;
  if (tid < 128) cred[tid] = 0.f;
  __syncthreads();
  const floatx4 z4 = {0.f, 0.f, 0.f, 0.f};
  floatx4 acc[8];
#pragma unroll
  for (int ct = 0; ct < 8; ++ct) acc[ct] = z4;
  for (int k0 = 0; k0 < 256; k0 += 32) {
    bf16x8 a = ld8(X + (size_t)(rb + m16) * 256 + k0 + kg * 8);
#pragma unroll
    for (int ct = 0; ct < 8; ++ct)
      acc[ct] = MFMA16(a, ld8(PT + (ct * 16 + m16) * 256 + k0 + kg * 8), acc[ct]);
  }
  float rs[4];
#pragma unroll
  for (int r = 0; r < 4; ++r) rs[r] = rscale[rb + kg * 4 + r];
#pragma unroll
  for (int ct = 0; ct < 8; ++ct) {
    float s = 0.f;
#pragma unroll
    for (int r = 0; r < 4; ++r) s += expf(acc[ct][r] * rs[r]);
    atomicAdd(&cred[ct * 16 + m16], s);
  }
  __syncthreads();
  if (tid < 128) part[(size_t)blockIdx.x * 128 + tid] = cred[tid];
}

__global__ void k_colred(const float* __restrict__ part, float* __restrict__ out, int nblk) {
  const int tid = threadIdx.x;
  if (tid < 128) {
    float s = 0.f;
    for (int b = 0; b < nblk; ++b) s += part[(size_t)b * 128 + tid];
    out[tid] = s;
  }
}

// ---------------- gathered token features ----------------
__global__ __launch_bounds__(256) void k_feat_gather(const int* __restrict__ text,
                                                     const u16* __restrict__ TE,
                                                     const float* __restrict__ rs_term,
                                                     const u16* __restrict__ PT,
                                                     u16* __restrict__ Btok) {
  const int tid = threadIdx.x, lane = tid & 63, w = tid >> 6;
  const int m16 = lane & 15, kg = lane >> 4;
  const int rb = blockIdx.x * 64 + w * 16;
  const int ia = rb + m16;
  const int tok_a = text[(ia & 15) * 256 + (ia >> 4)];
  const floatx4 z4 = {0.f, 0.f, 0.f, 0.f};
  floatx4 acc[8];
#pragma unroll
  for (int ct = 0; ct < 8; ++ct) acc[ct] = z4;
  for (int k0 = 0; k0 < 256; k0 += 32) {
    bf16x8 a = ld8(TE + (size_t)tok_a * 256 + k0 + kg * 8);
#pragma unroll
    for (int ct = 0; ct < 8; ++ct)
      acc[ct] = MFMA16(a, ld8(PT + (ct * 16 + m16) * 256 + k0 + kg * 8), acc[ct]);
  }
  float rs[4];
#pragma unroll
  for (int r = 0; r < 4; ++r) {
    const int io = rb + kg * 4 + r;
    rs[r] = rs_term[text[(io & 15) * 256 + (io >> 4)]];
  }
#pragma unroll
  for (int ct = 0; ct < 8; ++ct)
#pragma unroll
    for (int r = 0; r < 4; ++r)
      Btok[(size_t)(rb + kg * 4 + r) * 128 + ct * 16 + m16] = f2bf(expf(acc[ct][r] * rs[r]));
}

// ---------------- colsum (ByN -> SBN) ----------------
__global__ __launch_bounds__(256) void k_colsum(const u16* __restrict__ X,
                                                float* __restrict__ out, int rows) {
  __shared__ float red[256];
  const int tid = threadIdx.x, d = tid & 127, g = tid >> 7;
  const int r0 = blockIdx.x * 256 + g, r1 = blockIdx.x * 256 + 256;
  float s = 0.f;
  for (int r = r0; r < r1; r += 2) s += bf2f(X[(size_t)r * 128 + d]);
  red[tid] = s;
  __syncthreads();
  if (tid < 128) atomicAdd(out + tid, red[tid] + red[tid + 128]);
}

// ---------------- per-state scalars ----------------
__global__ __launch_bounds__(256) void k_vecdots(
    const u16* __restrict__ AxS, const u16* __restrict__ AxP, const u16* __restrict__ ByN,
    const float* __restrict__ SBN, const float* __restrict__ SBT, const float* __restrict__ ex0,
    float* __restrict__ recip_r, float* __restrict__ recip_den,
    float* __restrict__ start_raw) {
  const int w = threadIdx.x >> 6, lane = threadIdx.x & 63;
  const int c = blockIdx.x * 4 + w;
  const int d = lane * 2;
  float a0 = bf2f(AxS[(size_t)c * 128 + d]), a1 = bf2f(AxS[(size_t)c * 128 + d + 1]);
  float t = wred64(a0 * SBN[d] + a1 * SBN[d + 1]);
  float p0 = bf2f(AxP[(size_t)c * 128 + d]), p1 = bf2f(AxP[(size_t)c * 128 + d + 1]);
  float p = wred64(p0 * SBT[d] + p1 * SBT[d + 1]);
  float y0 = bf2f(ByN[(size_t)c * 128 + d]), y1 = bf2f(ByN[(size_t)c * 128 + d + 1]);
  float s = wred64(y0 * ex0[d] + y1 * ex0[d + 1]);
  if (lane == 0) {
    recip_r[c] = 1.0f / t;
    recip_den[c] = 1.0f / p;
    start_raw[c] = s;
  }
}

__global__ void k_ssum(const float* __restrict__ start_raw, float* __restrict__ ssum) {
  __shared__ float red[256];
  const int tid = threadIdx.x;
  float s = 0.f;
  for (int i = tid; i < 4096; i += 256) s += start_raw[i];
  red[tid] = s;
  __syncthreads();
  for (int st = 128; st > 0; st >>= 1) {
    if (tid < st) red[tid] += red[tid + st];
    __syncthreads();
  }
  if (tid == 0) ssum[0] = red[0];
}

// ---------- wave-0 emission tile for timestep t ----------
__device__ __forceinline__ void emis16(const u16* __restrict__ Btok,
                                       const u16 (*AxPs)[128],
                                       const float* __restrict__ recip_den,
                                       int cbase, int t, int m16, int kg,
                                       float* emsh) {
  floatx4 acc = {0.f, 0.f, 0.f, 0.f};
#pragma unroll
  for (int k0 = 0; k0 < 128; k0 += 32)
    acc = MFMA16(ld8(Btok + (size_t)(t * 16 + m16) * 128 + k0 + kg * 8),
                 *(const bf16x8*)(&AxPs[m16][k0 + kg * 8]), acc);
  const float rd = recip_den[cbase + m16];
#pragma unroll
  for (int r = 0; r < 4; ++r) emsh[(kg * 4 + r) * 16 + m16] = acc[r] * rd;
}

// ---------------- persistent cooperative HMM forward (TT resident in LDS) ----------------
__global__ __launch_bounds__(256) void k_forward(
    const u16* __restrict__ AxS, const u16* __restrict__ ByN, const u16* __restrict__ AxP,
    const u16* __restrict__ Btok,
    const float* __restrict__ recip_r, const float* __restrict__ recip_den,
    const float* __restrict__ start_raw, const float* __restrict__ ssum,
    u16* __restrict__ U0, u16* __restrict__ U1,
    float* __restrict__ Spart, const int* __restrict__ flag, u16* __restrict__ outp) {
  cg::grid_group grid = cg::this_grid();
  __shared__ __align__(16) u16 TTl[16][4104];
  __shared__ __align__(16) u16 AxPs[16][128];
  __shared__ __align__(16) float red[4][256];  // prologue alias: ByNs[16][128] u16
  __shared__ float red2[256];
  __shared__ float emsh[256];
  __shared__ float recipS[16];
  __shared__ float evacc[16];
  const int tid = threadIdx.x, lane = tid & 63, w = tid >> 6;
  const int m16 = lane & 15, kg = lane >> 4;
  const int b = blockIdx.x, cbase = b * 16;
  const floatx4 z4 = {0.f, 0.f, 0.f, 0.f};

  // stage AxP / ByN slices for this block's 16 columns
  {
    u16(*ByNs)[128] = (u16(*)[128])red;
    const int r = tid >> 4, d = (tid & 15) * 8;
    *(uint4*)(&AxPs[r][d]) = *(const uint4*)(AxP + (size_t)(cbase + r) * 128 + d);
    *(uint4*)(&ByNs[r][d]) = *(const uint4*)(ByN + (size_t)(cbase + r) * 128 + d);
  }
  if (tid < 16) evacc[tid] = 0.f;
  __syncthreads();
  // TTl[r][c] = trans[c][cbase+r] = (AxS[c]·ByN[cbase+r]) * recip_r[c]
  // MFMA D[row][col] = AxS[chunk*16+row]·ByNs[col]; row=kg*4+rr, col=m16
  {
    const u16(*ByNs)[128] = (const u16(*)[128])red;
    for (int chunk = w; chunk < 256; chunk += 4) {
      floatx4 acc = z4;
#pragma unroll
      for (int k0 = 0; k0 < 128; k0 += 32)
        acc = MFMA16(ld8(AxS + (size_t)(chunk * 16 + m16) * 128 + k0 + kg * 8),
                     *(const bf16x8*)(&ByNs[m16][k0 + kg * 8]), acc);
      const int c0 = chunk * 16 + kg * 4;
#pragma unroll
      for (int rr = 0; rr < 4; ++rr)
        TTl[m16][c0 + rr] = f2bf(acc[rr] * recip_r[c0 + rr]);
    }
  }
  __syncthreads();

  // t = 0
  if (w == 0) emis16(Btok, AxPs, recip_den, cbase, 0, m16, kg, emsh);
  __syncthreads();
  {
    const int n = tid >> 4, c = tid & 15;
    float u = start_raw[cbase + c] * emsh[tid];
    U0[n * 4096 + cbase + c] = f2bf(u);
    red2[tid] = u;
  }
  __syncthreads();
  if (tid < 16) {
    float s = 0.f;
    for (int j = 0; j < 16; ++j) s += red2[tid * 16 + j];
    Spart[b * 16 + tid] = s;
  }
  grid.sync();

  const u16* Uprev = U0;
  u16* Ucur = U1;
  for (int t = 1; t < 256; ++t) {
    // A) reduce S_{t-1} over 256 block-partials
    {
      const int n = tid & 15, g = tid >> 4;
      const float* sp = Spart + ((t - 1) & 1) * 4096;
      float ps = 0.f;
#pragma unroll
      for (int j = 0; j < 16; ++j) ps += sp[(g * 16 + j) * 16 + n];
      red2[tid] = ps;
    }
    __syncthreads();
    if (tid < 16) {
      float s = 0.f;
#pragma unroll
      for (int g = 0; g < 16; ++g) s += red2[g * 16 + tid];
      recipS[tid] = 1.0f / s;
      if (b == 0) evacc[tid] += logf(s);
    }
    // B) emission (wave0) + main [16x4096]@[4096x16] matmul (K split over 4 waves)
    if (w == 0) emis16(Btok, AxPs, recip_den, cbase, t, m16, kg, emsh);
    {
      const int kw = w * 1024 + kg * 8;
      floatx4 acc0 = z4, acc1 = z4;
      const u16* arow = Uprev + m16 * 4096 + kw;
#pragma unroll 4
      for (int kk = 0; kk < 1024; kk += 64) {
        acc0 = MFMA16(ld8(arow + kk), *(const bf16x8*)(&TTl[m16][kw + kk]), acc0);
        acc1 = MFMA16(ld8(arow + kk + 32), *(const bf16x8*)(&TTl[m16][kw + kk + 32]), acc1);
      }
      acc0 = acc0 + acc1;
#pragma unroll
      for (int r = 0; r < 4; ++r) red[w][(kg * 4 + r) * 16 + m16] = acc0[r];
    }
    __syncthreads();
    // C) epilogue
    {
      const int n = tid >> 4, c = tid & 15;
      float v = red[0][tid] + red[1][tid] + red[2][tid] + red[3][tid];
      float u = v * recipS[n] * emsh[tid];
      Ucur[n * 4096 + cbase + c] = f2bf(u);
      red2[tid] = u;
    }
    __syncthreads();
    if (tid < 16) {
      float s = 0.f;
      for (int j = 0; j < 16; ++j) s += red2[tid * 16 + j];
      Spart[(t & 1) * 4096 + b * 16 + tid] = s;
    }
    const u16* tmp = Uprev; Uprev = Ucur; Ucur = (u16*)tmp;
    grid.sync();
  }
  if (b == 0) {
    const int n = tid & 15, g = tid >> 4;
    const float* sp = Spart + 4096;  // t=255 partials
    float ps = 0.f;
    for (int j = 0; j < 16; ++j) ps += sp[(g * 16 + j) * 16 + n];
    red2[tid] = ps;
    __syncthreads();
    if (tid < 16) {
      float s = 0.f;
      for (int g2 = 0; g2 < 16; ++g2) s += red2[g2 * 16 + tid];
      evacc[tid] += logf(s);
    }
    __syncthreads();
    if (tid == 0) {
      float ev = 0.f;
      for (int i = 0; i < 16; ++i) ev += evacc[i];
      ev -= 16.0f * logf(ssum[0]);
      store_final(outp, ev, *flag);
    }
  }
}

// ---------------- fallback: TT[c'][c] materialized ----------------
__global__ __launch_bounds__(256) void k_pair(const u16* __restrict__ A, const u16* __restrict__ B,
                                              const float* __restrict__ cscale,
                                              u16* __restrict__ OUT) {
  const int tid = threadIdx.x, lane = tid & 63, w = tid >> 6;
  const int m16 = lane & 15, kg = lane >> 4;
  const int mb = blockIdx.y * 128 + w * 32;
  const int nb = blockIdx.x * 128;
  const floatx4 z4 = {0.f, 0.f, 0.f, 0.f};
  floatx4 acc[2][8];
#pragma unroll
  for (int rt = 0; rt < 2; ++rt)
#pragma unroll
    for (int ct = 0; ct < 8; ++ct) acc[rt][ct] = z4;
  for (int k0 = 0; k0 < 128; k0 += 32) {
    bf16x8 a0 = ld8(A + (size_t)(mb + m16) * 128 + k0 + kg * 8);
    bf16x8 a1 = ld8(A + (size_t)(mb + 16 + m16) * 128 + k0 + kg * 8);
#pragma unroll
    for (int ct = 0; ct < 8; ++ct) {
      bf16x8 bb = ld8(B + (size_t)(nb + ct * 16 + m16) * 128 + k0 + kg * 8);
      acc[0][ct] = MFMA16(a0, bb, acc[0][ct]);
      acc[1][ct] = MFMA16(a1, bb, acc[1][ct]);
    }
  }
  float cs[8];
#pragma unroll
  for (int ct = 0; ct < 8; ++ct) cs[ct] = cscale[nb + ct * 16 + m16];
#pragma unroll
  for (int rt = 0; rt < 2; ++rt)
#pragma unroll
    for (int ct = 0; ct < 8; ++ct)
#pragma unroll
      for (int r = 0; r < 4; ++r)
        OUT[(size_t)(mb + rt * 16 + kg * 4 + r) * 4096 + nb + ct * 16 + m16] =
            f2bf(acc[rt][ct][r] * cs[ct]);
}

// ---------------- fallback: one HMM step per launch ----------------
__global__ __launch_bounds__(256) void k_step(
    const u16* __restrict__ TT, const u16* __restrict__ Btok, const u16* __restrict__ AxP,
    const float* __restrict__ recip_den, const float* __restrict__ start_raw,
    const u16* __restrict__ Uprev, u16* __restrict__ Ucur,
    float* __restrict__ Spart, float* __restrict__ Ev, int t) {
  __shared__ __align__(16) u16 AxPs[16][128];
  __shared__ __align__(16) float red[4][256];
  __shared__ float red2[256];
  __shared__ float emsh[256];
  __shared__ float recipS[16];
  const int tid = threadIdx.x, lane = tid & 63, w = tid >> 6;
  const int m16 = lane & 15, kg = lane >> 4;
  const int b = blockIdx.x, cbase = b * 16;
  const floatx4 z4 = {0.f, 0.f, 0.f, 0.f};

  {
    const int r = tid >> 4, d = (tid & 15) * 8;
    *(uint4*)(&AxPs[r][d]) = *(const uint4*)(AxP + (size_t)(cbase + r) * 128 + d);
  }
  __syncthreads();
  if (w == 0) emis16(Btok, AxPs, recip_den, cbase, t, m16, kg, emsh);
  if (t == 0) {
    __syncthreads();
    const int n = tid >> 4, c = tid & 15;
    float u = start_raw[cbase + c] * emsh[tid];
    Ucur[n * 4096 + cbase + c] = f2bf(u);
    red2[tid] = u;
    __syncthreads();
    if (tid < 16) {
      float s = 0.f;
      for (int j = 0; j < 16; ++j) s += red2[tid * 16 + j];
      Spart[b * 16 + tid] = s;
    }
    return;
  }
  {
    const int n = tid & 15, g = tid >> 4;
    const float* sp = Spart + ((t - 1) & 1) * 4096;
    float ps = 0.f;
#pragma unroll
    for (int j = 0; j < 16; ++j) ps += sp[(g * 16 + j) * 16 + n];
    red2[tid] = ps;
  }
  __syncthreads();
  if (tid < 16) {
    float s = 0.f;
#pragma unroll
    for (int g = 0; g < 16; ++g) s += red2[g * 16 + tid];
    recipS[tid] = 1.0f / s;
    if (b == 0) Ev[tid] += logf(s);
  }
  {
    const int kw = w * 1024 + kg * 8;
    floatx4 acc0 = z4, acc1 = z4;
    const u16* arow = Uprev + m16 * 4096 + kw;
    const u16* brow = TT + (size_t)(cbase + m16) * 4096 + kw;
#pragma unroll 4
    for (int kk = 0; kk < 1024; kk += 64) {
      acc0 = MFMA16(ld8(arow + kk), ld8(brow + kk), acc0);
      acc1 = MFMA16(ld8(arow + kk + 32), ld8(brow + kk + 32), acc1);
    }
    acc0 = acc0 + acc1;
#pragma unroll
    for (int r = 0; r < 4; ++r) red[w][(kg * 4 + r) * 16 + m16] = acc0[r];
  }
  __syncthreads();
  {
    const int n = tid >> 4, c = tid & 15;
    float v = red[0][tid] + red[1][tid] + red[2][tid] + red[3][tid];
    float u = v * recipS[n] * emsh[tid];
    Ucur[n * 4096 + cbase + c] = f2bf(u);
    red2[tid] = u;
  }
  __syncthreads();
  if (tid < 16) {
    float s = 0.f;
    for (int j = 0; j < 16; ++j) s += red2[tid * 16 + j];
    Spart[(t & 1) * 4096 + b * 16 + tid] = s;
  }
}

__global__ __launch_bounds__(256) void k_fin(const float* __restrict__ Spart,
                                             const float* __restrict__ Ev,
                                             const float* __restrict__ ssum,
                                             const int* __restrict__ flag,
                                             u16* __restrict__ outp) {
  __shared__ float red2[256];
  __shared__ float fin[16];
  const int tid = threadIdx.x;
  const int n = tid & 15, g = tid >> 4;
  const float* sp = Spart + 4096;  // t=255
  float ps = 0.f;
  for (int j = 0; j < 16; ++j) ps += sp[(g * 16 + j) * 16 + n];
  red2[tid] = ps;
  __syncthreads();
  if (tid < 16) {
    float s = 0.f;
    for (int g2 = 0; g2 < 16; ++g2) s += red2[g2 * 16 + tid];
    fin[tid] = Ev[tid] + logf(s);
  }
  __syncthreads();
  if (tid == 0) {
    float ev = 0.f;
    for (int i = 0; i < 16; ++i) ev += fin[i];
    ev -= 16.0f * logf(ssum[0]);
    store_final(outp, ev, *flag);
  }
}

extern "C" void kernel_launch(void* const* d_in, const int* in_sizes, int n_in,
                              void* d_out, int out_size, void* d_ws, size_t ws_size,
                              hipStream_t stream) {
  (void)out_size;
  u16* outp = (u16*)d_out;
  if (n_in != 26 || in_sizes[25] != 128 * 256) {
    k_sentinel<<<1, 1, 0, stream>>>(outp, 5000.0f + (float)n_in);
    return;
  }
  const int* text = (const int*)d_in[0];

  char* base = (char*)d_ws;
  size_t off = 0;
  auto take = [&](size_t bytes) -> char* {
    char* p = base + off;
    off = (off + bytes + 255) & ~(size_t)255;
    return p;
  };
  int* flag = (int*)take(256);
  u16* c_se   = (u16*)take(256 * 2);
  u16* c_w[18];
  for (int i = 0; i < 18; ++i) c_w[i] = (u16*)take(((i & 1) ? 256 : 65536) * 2);
  u16* c_state = (u16*)take((size_t)1048576 * 2);
  u16* c_next  = (u16*)take((size_t)1048576 * 2);
  u16* c_pre   = (u16*)take((size_t)1048576 * 2);
  u16* c_term  = (u16*)take((size_t)8192000 * 2);
  u16* c_proj  = (u16*)take((size_t)32768 * 2);
  u16* projT  = (u16*)take(128 * 256 * 2);
  u16* twT1   = (u16*)take(65536 * 2);
  u16* twT2   = (u16*)take(65536 * 2);
  u16* twT3   = (u16*)take(65536 * 2);
  u16* twT4   = (u16*)take(65536 * 2);
  u16* ft     = (u16*)take((size_t)4096 * 256 * 2);
  float* rs_state = (float*)take(4096 * 4);
  float* rs_next  = (float*)take(4096 * 4);
  float* rs_ft    = (float*)take(4096 * 4);
  float* rs_term  = (float*)take(32000 * 4);
  u16* AxS    = (u16*)take((size_t)4096 * 128 * 2);
  u16* ByN    = (u16*)take((size_t)4096 * 128 * 2);
  u16* AxP    = (u16*)take((size_t)4096 * 128 * 2);
  u16* Btok   = (u16*)take((size_t)4096 * 128 * 2);
  float* SBTpart = (float*)take(500 * 128 * 4);
  float* zreg = (float*)take(2048);  // SBN[128] | SBT[128] | ssum[1] | Ev[16]
  float* SBN = zreg, *SBT = zreg + 128, *ssum = zreg + 256, *Ev = zreg + 257;
  float* recip_r   = (float*)take(4096 * 4);
  float* recip_den = (float*)take(4096 * 4);
  float* start_raw = (float*)take(4096 * 4);
  float* ex0       = (float*)take(128 * 4);
  u16* U0     = (u16*)take(16 * 4096 * 2);
  u16* U1     = (u16*)take(16 * 4096 * 2);
  float* Spart = (float*)take(2 * 4096 * 4);
  u16* TT     = (u16*)take((size_t)4096 * 4096 * 2);

  const float ws_mb = (float)(ws_size >> 20) > 900.f ? 900.f : (float)(ws_size >> 20);
  if (off > ws_size) {
    k_sentinel<<<1, 1, 0, stream>>>(outp, 1000.0f + ws_mb);
    return;
  }

  k_detect<<<1, 64, 0, stream>>>((const u32*)d_in[25], flag);
  k_sentinel<<<1, 1, 0, stream>>>(outp, -7777.0f);  // breadcrumb
  hipMemsetAsync(zreg, 0, 2048, stream);

  auto cvt = [&](const void* p, u16* dst, int n) {
    k_cvt<<<(n + 255) / 256, 256, 0, stream>>>((const float*)p, (const u16*)p, dst, n, flag);
  };
  cvt(d_in[2], c_se, 256);
  for (int i = 0; i < 18; ++i) cvt(d_in[3 + i], c_w[i], (i & 1) ? 256 : 65536);
  cvt(d_in[21], c_state, 1048576);
  cvt(d_in[22], c_next, 1048576);
  cvt(d_in[23], c_pre, 1048576);
  cvt(d_in[24], c_term, 8192000);
  cvt(d_in[25], c_proj, 32768);

  u16 *c_sw0 = c_w[0], *c_sb0 = c_w[1], *c_sw1 = c_w[2], *c_sb1 = c_w[3];
  u16 *c_sw2 = c_w[4], *c_sb2 = c_w[5], *c_sw3 = c_w[6], *c_sb3 = c_w[7];
  u16 *c_sw4 = c_w[8], *c_sb4 = c_w[9];
  u16 *c_tw1 = c_w[10], *c_tb1 = c_w[11], *c_tw2 = c_w[12], *c_tb2 = c_w[13];
  u16 *c_tw3 = c_w[14], *c_tb3 = c_w[15], *c_tw4 = c_w[16], *c_tb4 = c_w[17];

  k_transpose<<<128, 256, 0, stream>>>(c_proj, projT, 256, 128);
  k_transpose<<<256, 256, 0, stream>>>(c_tw1, twT1, 256, 256);
  k_transpose<<<256, 256, 0, stream>>>(c_tw2, twT2, 256, 256);
  k_transpose<<<256, 256, 0, stream>>>(c_tw3, twT3, 256, 256);
  k_transpose<<<256, 256, 0, stream>>>(c_tw4, twT4, 256, 256);
  k_start<<<1, 256, 0, stream>>>(c_se, c_sw0, c_sb0, c_sw1, c_sb1, c_sw2, c_sb2,
                                 c_sw3, c_sb3, c_sw4, c_sb4, c_proj, ex0);
  k_mlp<<<64, 256, 0, stream>>>(c_pre, twT1, c_tb1, twT2, c_tb2, twT3, c_tb3, twT4, c_tb4, ft);
  k_rownorm<<<1024, 256, 0, stream>>>(c_state, rs_state, 4096);
  k_rownorm<<<1024, 256, 0, stream>>>(c_next, rs_next, 4096);
  k_rownorm<<<1024, 256, 0, stream>>>(ft, rs_ft, 4096);
  k_rownorm<<<8000, 256, 0, stream>>>(c_term, rs_term, 32000);
  k_feat<<<64, 256, 0, stream>>>(c_state, rs_state, projT, AxS);
  k_feat<<<64, 256, 0, stream>>>(c_next, rs_next, projT, ByN);
  k_feat<<<64, 256, 0, stream>>>(ft, rs_ft, projT, AxP);
  k_feat_colsum<<<500, 256, 0, stream>>>(c_term, rs_term, projT, SBTpart);
  k_colred<<<1, 256, 0, stream>>>(SBTpart, SBT, 500);
  k_feat_gather<<<64, 256, 0, stream>>>(text, c_term, rs_term, projT, Btok);
  k_colsum<<<16, 256, 0, stream>>>(ByN, SBN, 4096);
  k_vecdots<<<1024, 256, 0, stream>>>(AxS, AxP, ByN, SBN, SBT, ex0, recip_r, recip_den,
                                      start_raw);
  k_ssum<<<1, 256, 0, stream>>>(start_raw, ssum);

  // primary: persistent cooperative kernel, TT in LDS, 1 grid.sync/step
  void* kargs[13] = {(void*)&AxS, (void*)&ByN, (void*)&AxP, (void*)&Btok,
                     (void*)&recip_r, (void*)&recip_den, (void*)&start_raw, (void*)&ssum,
                     (void*)&U0, (void*)&U1, (void*)&Spart, (void*)&flag, (void*)&outp};
  hipError_t cerr = hipLaunchCooperativeKernel((void*)k_forward, dim3(256), dim3(256),
                                               kargs, 0, stream);
  if (cerr != hipSuccess) {
    // fallback: verified launch-per-step chain
    k_pair<<<dim3(32, 32), 256, 0, stream>>>(ByN, AxS, recip_r, TT);
    k_step<<<256, 256, 0, stream>>>(TT, Btok, AxP, recip_den, start_raw, U0, U0, Spart, Ev, 0);
    for (int t = 1; t < 256; ++t) {
      const u16* up = ((t - 1) & 1) ? U1 : U0;
      u16* uc = (t & 1) ? U1 : U0;
      k_step<<<256, 256, 0, stream>>>(TT, Btok, AxP, recip_den, start_raw, up, uc, Spart, Ev, t);
    }
    k_fin<<<1, 256, 0, stream>>>(Spart, Ev, ssum, flag, outp);
  }
}

// Round 6
// 2472.564 us; speedup vs baseline: 3.5868x; 3.5868x over previous
//
#include <hip/hip_runtime.h>
#include <math.h>

typedef unsigned short u16;
typedef unsigned int u32;
typedef __bf16 bf16x8 __attribute__((ext_vector_type(8)));
typedef float floatx4 __attribute__((ext_vector_type(4)));

#define MFMA16(a, b, c) __builtin_amdgcn_mfma_f32_16x16x32_bf16((a), (b), (c), 0, 0, 0)

__device__ __forceinline__ float bf2f(u16 u) {
  u32 x = ((u32)u) << 16; float f; __builtin_memcpy(&f, &x, 4); return f;
}
__device__ __forceinline__ u16 f2bf(float f) {
  u32 x; __builtin_memcpy(&x, &f, 4);
  return (u16)((x + 0x7FFFu + ((x >> 16) & 1u)) >> 16);  // RNE
}
__device__ __forceinline__ void store_dual(u16* outp, float v) {
  u32 h = (u32)f2bf(v);
  *(u32*)outp = (h << 16) | h;
}
__device__ __forceinline__ bf16x8 ld8(const u16* p) { return *(const bf16x8*)p; }

__device__ __forceinline__ float wred64(float v) {
#pragma unroll
  for (int off = 32; off > 0; off >>= 1) v += __shfl_down(v, off, 64);
  return v;
}

__device__ __forceinline__ void store_final(u16* outp, float ev, int flag) {
  if (!(ev == ev) || fabsf(ev) > 1e37f) ev = -12345.0f - 1000.0f * (float)flag;
  if (flag) *(float*)outp = ev;
  else outp[0] = f2bf(ev);
}

// ---------------- diagnostics ----------------
__global__ void k_sentinel(u16* outp, float v) {
  if (threadIdx.x == 0 && blockIdx.x == 0) store_dual(outp, v);
}

// ---------------- input dtype detect: flag=1 if f32, 0 if bf16 ----------------
__global__ void k_detect(const u32* __restrict__ raw, int* __restrict__ flag) {
  if (threadIdx.x == 0 && blockIdx.x == 0) {
    int outliers = 0;
    for (int i = 0; i < 64; ++i) {
      u32 lo = raw[i] & 0xFFFFu;
      int e = (int)((lo >> 7) & 0xFF);
      if (e < 100 || e > 150) ++outliers;
    }
    *flag = (outliers > 16) ? 1 : 0;
  }
}

// ---------------- dtype-aware convert-to-bf16 ----------------
__global__ void k_cvt(const float* __restrict__ inf_, const u16* __restrict__ inb,
                      u16* __restrict__ out, int n, const int* __restrict__ flag) {
  int i = blockIdx.x * 256 + threadIdx.x;
  if (i >= n) return;
  out[i] = (*flag) ? f2bf(inf_[i]) : inb[i];
}

// ---------------- transpose (bf16), out[c][r] = in[r][c] ----------------
__global__ void k_transpose(const u16* __restrict__ in, u16* __restrict__ out, int R, int C) {
  int i = blockIdx.x * 256 + threadIdx.x;
  if (i < R * C) { int r = i / C, c = i - r * C; out[c * R + r] = in[i]; }
}

// ---------------- start-vector MLP (1 block) -> ex0[128] ----------------
__global__ __launch_bounds__(256) void k_start(
    const u16* __restrict__ se,
    const u16* __restrict__ sw0, const u16* __restrict__ sb0,
    const u16* __restrict__ sw1, const u16* __restrict__ sb1,
    const u16* __restrict__ sw2, const u16* __restrict__ sb2,
    const u16* __restrict__ sw3, const u16* __restrict__ sb3,
    const u16* __restrict__ sw4, const u16* __restrict__ sb4,
    const u16* __restrict__ proj, float* __restrict__ ex0) {
  __shared__ float xa[256], xb[256], xc[256], red[256];
  const int tid = threadIdx.x;
  xa[tid] = bf2f(se[tid]);
  __syncthreads();
  float acc = bf2f(sb0[tid]);
  for (int k = 0; k < 256; ++k) acc += xa[k] * bf2f(sw0[k * 256 + tid]);
  xb[tid] = acc;  // f0 (Linear, no relu)
  __syncthreads();
  acc = bf2f(sb1[tid]);
  for (int k = 0; k < 256; ++k) acc += xb[k] * bf2f(sw1[k * 256 + tid]);
  xc[tid] = fmaxf(acc, 0.f);
  __syncthreads();
  acc = bf2f(sb2[tid]);
  for (int k = 0; k < 256; ++k) acc += xc[k] * bf2f(sw2[k * 256 + tid]);
  xa[tid] = fmaxf(acc, 0.f) + xb[tid];  // f1
  __syncthreads();
  acc = bf2f(sb3[tid]);
  for (int k = 0; k < 256; ++k) acc += xa[k] * bf2f(sw3[k * 256 + tid]);
  xc[tid] = fmaxf(acc, 0.f);
  __syncthreads();
  acc = bf2f(sb4[tid]);
  for (int k = 0; k < 256; ++k) acc += xc[k] * bf2f(sw4[k * 256 + tid]);
  xb[tid] = fmaxf(acc, 0.f) + xa[tid];  // f2
  __syncthreads();
  red[tid] = xb[tid] * xb[tid];
  __syncthreads();
  for (int s = 128; s > 0; s >>= 1) {
    if (tid < s) red[tid] += red[tid + s];
    __syncthreads();
  }
  const float rs = rsqrtf(red[0]);
  xa[tid] = xb[tid] * rs;
  __syncthreads();
  if (tid < 128) {
    float a = 0.f;
    for (int k = 0; k < 256; ++k) a += xa[k] * bf2f(proj[k * 128 + tid]);
    ex0[tid] = expf(a);
  }
}

// ---------------- preterminal MLP: ft = res(res(X0)) via MFMA ----------------
__global__ __launch_bounds__(256) void k_mlp(
    const u16* __restrict__ X0,
    const u16* __restrict__ w1T, const u16* __restrict__ b1,
    const u16* __restrict__ w2T, const u16* __restrict__ b2,
    const u16* __restrict__ w3T, const u16* __restrict__ b3,
    const u16* __restrict__ w4T, const u16* __restrict__ b4,
    u16* __restrict__ FT) {
  __shared__ __align__(16) u16 Y[2][64][264];
  const int tid = threadIdx.x, lane = tid & 63, w = tid >> 6;
  const int m16 = lane & 15, kg = lane >> 4;
  const int rbl = w * 16;
  const int rbg = blockIdx.x * 64 + rbl;
  const floatx4 z4 = {0.f, 0.f, 0.f, 0.f};
  floatx4 acc[16];

#pragma unroll
  for (int ct = 0; ct < 16; ++ct) acc[ct] = z4;
  for (int k0 = 0; k0 < 256; k0 += 32) {
    bf16x8 a = ld8(X0 + (size_t)(rbg + m16) * 256 + k0 + kg * 8);
#pragma unroll
    for (int ct = 0; ct < 16; ++ct)
      acc[ct] = MFMA16(a, ld8(w1T + (ct * 16 + m16) * 256 + k0 + kg * 8), acc[ct]);
  }
#pragma unroll
  for (int ct = 0; ct < 16; ++ct) {
    const int col = ct * 16 + m16;
    const float bv = bf2f(b1[col]);
#pragma unroll
    for (int r = 0; r < 4; ++r)
      Y[0][rbl + kg * 4 + r][col] = f2bf(fmaxf(acc[ct][r] + bv, 0.f));
  }
  __syncthreads();
#pragma unroll
  for (int ct = 0; ct < 16; ++ct) acc[ct] = z4;
  for (int k0 = 0; k0 < 256; k0 += 32) {
    bf16x8 a = *(const bf16x8*)(&Y[0][rbl + m16][k0 + kg * 8]);
#pragma unroll
    for (int ct = 0; ct < 16; ++ct)
      acc[ct] = MFMA16(a, ld8(w2T + (ct * 16 + m16) * 256 + k0 + kg * 8), acc[ct]);
  }
#pragma unroll
  for (int ct = 0; ct < 16; ++ct) {
    const int col = ct * 16 + m16;
    const float bv = bf2f(b2[col]);
#pragma unroll
    for (int r = 0; r < 4; ++r) {
      const int gr = rbg + kg * 4 + r;
      float v = fmaxf(acc[ct][r] + bv, 0.f) + bf2f(X0[(size_t)gr * 256 + col]);
      Y[1][rbl + kg * 4 + r][col] = f2bf(v);
    }
  }
  __syncthreads();
#pragma unroll
  for (int ct = 0; ct < 16; ++ct) acc[ct] = z4;
  for (int k0 = 0; k0 < 256; k0 += 32) {
    bf16x8 a = *(const bf16x8*)(&Y[1][rbl + m16][k0 + kg * 8]);
#pragma unroll
    for (int ct = 0; ct < 16; ++ct)
      acc[ct] = MFMA16(a, ld8(w3T + (ct * 16 + m16) * 256 + k0 + kg * 8), acc[ct]);
  }
#pragma unroll
  for (int ct = 0; ct < 16; ++ct) {
    const int col = ct * 16 + m16;
    const float bv = bf2f(b3[col]);
#pragma unroll
    for (int r = 0; r < 4; ++r)
      Y[0][rbl + kg * 4 + r][col] = f2bf(fmaxf(acc[ct][r] + bv, 0.f));
  }
  __syncthreads();
#pragma unroll
  for (int ct = 0; ct < 16; ++ct) acc[ct] = z4;
  for (int k0 = 0; k0 < 256; k0 += 32) {
    bf16x8 a = *(const bf16x8*)(&Y[0][rbl + m16][k0 + kg * 8]);
#pragma unroll
    for (int ct = 0; ct < 16; ++ct)
      acc[ct] = MFMA16(a, ld8(w4T + (ct * 16 + m16) * 256 + k0 + kg * 8), acc[ct]);
  }
#pragma unroll
  for (int ct = 0; ct < 16; ++ct) {
    const int col = ct * 16 + m16;
    const float bv = bf2f(b4[col]);
#pragma unroll
    for (int r = 0; r < 4; ++r) {
      const int rl = rbl + kg * 4 + r;
      float v = fmaxf(acc[ct][r] + bv, 0.f) + bf2f(Y[1][rl][col]);
      FT[(size_t)(rbg + kg * 4 + r) * 256 + col] = f2bf(v);
    }
  }
}

// ---------------- per-row 1/||x|| over 256 cols ----------------
__global__ __launch_bounds__(256) void k_rownorm(const u16* __restrict__ X,
                                                 float* __restrict__ rscale, int rows) {
  const int w = threadIdx.x >> 6, lane = threadIdx.x & 63;
  const int row = blockIdx.x * 4 + w;
  if (row >= rows) return;
  const u16* p = X + (size_t)row * 256 + lane * 4;
  float s = 0.f;
#pragma unroll
  for (int i = 0; i < 4; ++i) { float v = bf2f(p[i]); s += v * v; }
  s = wred64(s);
  if (lane == 0) rscale[row] = rsqrtf(s);
}

// ---------------- features: OUT[r][d] = exp(rscale[r] * X[r]·projT[d]) ----------------
__global__ __launch_bounds__(256) void k_feat(const u16* __restrict__ X,
                                              const float* __restrict__ rscale,
                                              const u16* __restrict__ PT,
                                              u16* __restrict__ OUT) {
  const int tid = threadIdx.x, lane = tid & 63, w = tid >> 6;
  const int m16 = lane & 15, kg = lane >> 4;
  const int rb = blockIdx.x * 64 + w * 16;
  const floatx4 z4 = {0.f, 0.f, 0.f, 0.f};
  floatx4 acc[8];
#pragma unroll
  for (int ct = 0; ct < 8; ++ct) acc[ct] = z4;
  for (int k0 = 0; k0 < 256; k0 += 32) {
    bf16x8 a = ld8(X + (size_t)(rb + m16) * 256 + k0 + kg * 8);
#pragma unroll
    for (int ct = 0; ct < 8; ++ct)
      acc[ct] = MFMA16(a, ld8(PT + (ct * 16 + m16) * 256 + k0 + kg * 8), acc[ct]);
  }
  float rs[4];
#pragma unroll
  for (int r = 0; r < 4; ++r) rs[r] = rscale[rb + kg * 4 + r];
#pragma unroll
  for (int ct = 0; ct < 8; ++ct)
#pragma unroll
    for (int r = 0; r < 4; ++r)
      OUT[(size_t)(rb + kg * 4 + r) * 128 + ct * 16 + m16] = f2bf(expf(acc[ct][r] * rs[r]));
}

// ---------------- term features fused with column-sum ----------------
__global__ __launch_bounds__(256) void k_feat_colsum(const u16* __restrict__ X,
                                                     const float* __restrict__ rscale,
                                                     const u16* __restrict__ PT,
                                                     float* __restrict__ part) {
  __shared__ float cred[128];
  const int tid = threadIdx.x, lane = tid & 63, w = tid >> 6;
  const int m16 = lane & 15, kg = lane >> 4;
  const int rb = blockIdx.x * 64 + w * 16;
  if (tid < 128) cred[tid] = 0.f;
  __syncthreads();
  const floatx4 z4 = {0.f, 0.f, 0.f, 0.f};
  floatx4 acc[8];
#pragma unroll
  for (int ct = 0; ct < 8; ++ct) acc[ct] = z4;
  for (int k0 = 0; k0 < 256; k0 += 32) {
    bf16x8 a = ld8(X + (size_t)(rb + m16) * 256 + k0 + kg * 8);
#pragma unroll
    for (int ct = 0; ct < 8; ++ct)
      acc[ct] = MFMA16(a, ld8(PT + (ct * 16 + m16) * 256 + k0 + kg * 8), acc[ct]);
  }
  float rs[4];
#pragma unroll
  for (int r = 0; r < 4; ++r) rs[r] = rscale[rb + kg * 4 + r];
#pragma unroll
  for (int ct = 0; ct < 8; ++ct) {
    float s = 0.f;
#pragma unroll
    for (int r = 0; r < 4; ++r) s += expf(acc[ct][r] * rs[r]);
    atomicAdd(&cred[ct * 16 + m16], s);
  }
  __syncthreads();
  if (tid < 128) part[(size_t)blockIdx.x * 128 + tid] = cred[tid];
}

__global__ void k_colred(const float* __restrict__ part, float* __restrict__ out, int nblk) {
  const int tid = threadIdx.x;
  if (tid < 128) {
    float s = 0.f;
    for (int b = 0; b < nblk; ++b) s += part[(size_t)b * 128 + tid];
    out[tid] = s;
  }
}

// ---------------- gathered token features ----------------
__global__ __launch_bounds__(256) void k_feat_gather(const int* __restrict__ text,
                                                     const u16* __restrict__ TE,
                                                     const float* __restrict__ rs_term,
                                                     const u16* __restrict__ PT,
                                                     u16* __restrict__ Btok) {
  const int tid = threadIdx.x, lane = tid & 63, w = tid >> 6;
  const int m16 = lane & 15, kg = lane >> 4;
  const int rb = blockIdx.x * 64 + w * 16;
  const int ia = rb + m16;
  const int tok_a = text[(ia & 15) * 256 + (ia >> 4)];
  const floatx4 z4 = {0.f, 0.f, 0.f, 0.f};
  floatx4 acc[8];
#pragma unroll
  for (int ct = 0; ct < 8; ++ct) acc[ct] = z4;
  for (int k0 = 0; k0 < 256; k0 += 32) {
    bf16x8 a = ld8(TE + (size_t)tok_a * 256 + k0 + kg * 8);
#pragma unroll
    for (int ct = 0; ct < 8; ++ct)
      acc[ct] = MFMA16(a, ld8(PT + (ct * 16 + m16) * 256 + k0 + kg * 8), acc[ct]);
  }
  float rs[4];
#pragma unroll
  for (int r = 0; r < 4; ++r) {
    const int io = rb + kg * 4 + r;
    rs[r] = rs_term[text[(io & 15) * 256 + (io >> 4)]];
  }
#pragma unroll
  for (int ct = 0; ct < 8; ++ct)
#pragma unroll
    for (int r = 0; r < 4; ++r)
      Btok[(size_t)(rb + kg * 4 + r) * 128 + ct * 16 + m16] = f2bf(expf(acc[ct][r] * rs[r]));
}

// ---------------- colsum (ByN -> SBN) ----------------
__global__ __launch_bounds__(256) void k_colsum(const u16* __restrict__ X,
                                                float* __restrict__ out, int rows) {
  __shared__ float red[256];
  const int tid = threadIdx.x, d = tid & 127, g = tid >> 7;
  const int r0 = blockIdx.x * 256 + g, r1 = blockIdx.x * 256 + 256;
  float s = 0.f;
  for (int r = r0; r < r1; r += 2) s += bf2f(X[(size_t)r * 128 + d]);
  red[tid] = s;
  __syncthreads();
  if (tid < 128) atomicAdd(out + tid, red[tid] + red[tid + 128]);
}

// ---------------- per-state scalars ----------------
__global__ __launch_bounds__(256) void k_vecdots(
    const u16* __restrict__ AxS, const u16* __restrict__ AxP, const u16* __restrict__ ByN,
    const float* __restrict__ SBN, const float* __restrict__ SBT, const float* __restrict__ ex0,
    float* __restrict__ recip_r, float* __restrict__ recip_den,
    float* __restrict__ start_raw) {
  const int w = threadIdx.x >> 6, lane = threadIdx.x & 63;
  const int c = blockIdx.x * 4 + w;
  const int d = lane * 2;
  float a0 = bf2f(AxS[(size_t)c * 128 + d]), a1 = bf2f(AxS[(size_t)c * 128 + d + 1]);
  float t = wred64(a0 * SBN[d] + a1 * SBN[d + 1]);
  float p0 = bf2f(AxP[(size_t)c * 128 + d]), p1 = bf2f(AxP[(size_t)c * 128 + d + 1]);
  float p = wred64(p0 * SBT[d] + p1 * SBT[d + 1]);
  float y0 = bf2f(ByN[(size_t)c * 128 + d]), y1 = bf2f(ByN[(size_t)c * 128 + d + 1]);
  float s = wred64(y0 * ex0[d] + y1 * ex0[d + 1]);
  if (lane == 0) {
    recip_r[c] = 1.0f / t;
    recip_den[c] = 1.0f / p;
    start_raw[c] = s;
  }
}

__global__ void k_ssum(const float* __restrict__ start_raw, float* __restrict__ ssum) {
  __shared__ float red[256];
  const int tid = threadIdx.x;
  float s = 0.f;
  for (int i = tid; i < 4096; i += 256) s += start_raw[i];
  red[tid] = s;
  __syncthreads();
  for (int st = 128; st > 0; st >>= 1) {
    if (tid < st) red[tid] += red[tid + st];
    __syncthreads();
  }
  if (tid == 0) ssum[0] = red[0];
}

// ---------------- AxS2T[d][c] = AxS[c][d] * recip_r[c]  ([128 x 4096] bf16) ----------------
__global__ void k_foldT(const u16* __restrict__ AxS, const float* __restrict__ recip_r,
                        u16* __restrict__ AxS2T) {
  int i = blockIdx.x * 256 + threadIdx.x;  // 128*4096
  if (i >= 128 * 4096) return;
  int d = i >> 12, c = i & 4095;
  AxS2T[i] = f2bf(bf2f(AxS[(size_t)c * 128 + d]) * recip_r[c]);
}

// ---------------- EM[nt][c] = (A[nt]·B[c]) * cscale[c], K=128 ----------------
__global__ __launch_bounds__(256) void k_pair(const u16* __restrict__ A, const u16* __restrict__ B,
                                              const float* __restrict__ cscale,
                                              u16* __restrict__ OUT) {
  const int tid = threadIdx.x, lane = tid & 63, w = tid >> 6;
  const int m16 = lane & 15, kg = lane >> 4;
  const int mb = blockIdx.y * 128 + w * 32;
  const int nb = blockIdx.x * 128;
  const floatx4 z4 = {0.f, 0.f, 0.f, 0.f};
  floatx4 acc[2][8];
#pragma unroll
  for (int rt = 0; rt < 2; ++rt)
#pragma unroll
    for (int ct = 0; ct < 8; ++ct) acc[rt][ct] = z4;
  for (int k0 = 0; k0 < 128; k0 += 32) {
    bf16x8 a0 = ld8(A + (size_t)(mb + m16) * 128 + k0 + kg * 8);
    bf16x8 a1 = ld8(A + (size_t)(mb + 16 + m16) * 128 + k0 + kg * 8);
#pragma unroll
    for (int ct = 0; ct < 8; ++ct) {
      bf16x8 bb = ld8(B + (size_t)(nb + ct * 16 + m16) * 128 + k0 + kg * 8);
      acc[0][ct] = MFMA16(a0, bb, acc[0][ct]);
      acc[1][ct] = MFMA16(a1, bb, acc[1][ct]);
    }
  }
  float cs[8];
#pragma unroll
  for (int ct = 0; ct < 8; ++ct) cs[ct] = cscale[nb + ct * 16 + m16];
#pragma unroll
  for (int rt = 0; rt < 2; ++rt)
#pragma unroll
    for (int ct = 0; ct < 8; ++ct)
#pragma unroll
      for (int r = 0; r < 4; ++r)
        OUT[(size_t)(mb + rt * 16 + kg * 4 + r) * 4096 + nb + ct * 16 + m16] =
            f2bf(acc[rt][ct][r] * cs[ct]);
}

// ---------- contract: Vout[n][d] = sum_c ush[n][c] * AxS2T[d][cb+c], c over 256 ----------
__device__ __forceinline__ void contract256(const u16 (*ush)[264], const u16* __restrict__ AxS2T,
                                            int cb, u16* __restrict__ vout,
                                            int m16, int kg, int w) {
  const floatx4 z4 = {0.f, 0.f, 0.f, 0.f};
#pragma unroll
  for (int ct2 = 0; ct2 < 2; ++ct2) {
    const int ct = w * 2 + ct2;
    floatx4 acc = z4;
#pragma unroll
    for (int k0 = 0; k0 < 256; k0 += 32)
      acc = MFMA16(*(const bf16x8*)(&ush[m16][k0 + kg * 8]),
                   ld8(AxS2T + (size_t)(ct * 16 + m16) * 4096 + cb + k0 + kg * 8), acc);
#pragma unroll
    for (int r = 0; r < 4; ++r)
      vout[(kg * 4 + r) * 128 + ct * 16 + m16] = f2bf(acc[r]);
  }
}

// ---------------- t=0: u0 = start_raw * EM[0], v0 partial, S0 partial ----------------
__global__ __launch_bounds__(256) void k_vinit(const u16* __restrict__ EM,
                                               const float* __restrict__ start_raw,
                                               const u16* __restrict__ AxS2T,
                                               u16* __restrict__ Vpart,
                                               float* __restrict__ Spart) {
  __shared__ __align__(16) u16 ush[16][264];
  __shared__ float red2[256];
  const int tid = threadIdx.x, lane = tid & 63, w = tid >> 6;
  const int m16 = lane & 15, kg = lane >> 4;
  const int b = blockIdx.x, cb = b * 256;
  const int n = tid >> 4, cg = tid & 15;
  float s = 0.f;
#pragma unroll
  for (int j = 0; j < 16; ++j) {
    const int c = cg * 16 + j;
    float u = start_raw[cb + c] * bf2f(EM[(size_t)n * 4096 + cb + c]);
    ush[n][c] = f2bf(u);
    s += u;
  }
  red2[tid] = s;  // tid = n*16+cg
  __syncthreads();
  if (tid < 16) {
    float S = 0.f;
#pragma unroll
    for (int j = 0; j < 16; ++j) S += red2[tid * 16 + j];
    Spart[b * 16 + tid] = S;  // buf 0
  }
  contract256(ush, AxS2T, cb, Vpart + b * 2048, m16, kg, w);  // buf 0
}

// ---------------- one low-rank HMM step ----------------
__global__ __launch_bounds__(256) void k_vstep(const u16* __restrict__ EM,
                                               const u16* __restrict__ ByN,
                                               const u16* __restrict__ AxS2T,
                                               u16* __restrict__ Vpart,
                                               float* __restrict__ Spart,
                                               float* __restrict__ Ev, int t) {
  __shared__ __align__(16) u16 vsh[16][136];
  __shared__ __align__(16) u16 ush[16][264];
  __shared__ float red2[256];
  __shared__ float recipS[16];
  const int tid = threadIdx.x, lane = tid & 63, w = tid >> 6;
  const int m16 = lane & 15, kg = lane >> 4;
  const int b = blockIdx.x, cb = b * 256;
  const int pbuf = (t - 1) & 1, cbuf = t & 1;

  // phase 1: reduce 16 v-partials + S-partials
  const int n1 = tid >> 4, d8 = (tid & 15) * 8;
  float vs[8];
#pragma unroll
  for (int j = 0; j < 8; ++j) vs[j] = 0.f;
  const u16* vp = Vpart + pbuf * 32768 + n1 * 128 + d8;
#pragma unroll
  for (int p = 0; p < 16; ++p) {
    bf16x8 v8 = ld8(vp + p * 2048);
#pragma unroll
    for (int j = 0; j < 8; ++j) vs[j] += (float)v8[j];
  }
  red2[(tid & 15) * 16 + (tid >> 4)] = Spart[pbuf * 256 + tid];
  __syncthreads();
  if (tid < 16) {
    float S = 0.f;
#pragma unroll
    for (int j = 0; j < 16; ++j) S += red2[tid * 16 + j];
    recipS[tid] = 1.0f / S;
    if (b == 0) Ev[tid] += logf(S);
  }
  __syncthreads();
  {
    const float rS = recipS[n1];
    u16 tmp[8];
#pragma unroll
    for (int j = 0; j < 8; ++j) tmp[j] = f2bf(vs[j] * rS);
    *(uint4*)(&vsh[n1][d8]) = *(uint4*)tmp;
  }
  __syncthreads();

  // phase 2: expand u[n][c] = (v·ByN[c]) * EM[t][n][c]
  const floatx4 z4 = {0.f, 0.f, 0.f, 0.f};
#pragma unroll
  for (int ct2 = 0; ct2 < 4; ++ct2) {
    const int ct = w * 4 + ct2;
    const int c = cb + ct * 16 + m16;
    u16 emv[4];
#pragma unroll
    for (int r = 0; r < 4; ++r)
      emv[r] = EM[(size_t)(t * 16 + kg * 4 + r) * 4096 + c];
    floatx4 acc = z4;
#pragma unroll
    for (int k0 = 0; k0 < 128; k0 += 32)
      acc = MFMA16(*(const bf16x8*)(&vsh[m16][k0 + kg * 8]),
                   ld8(ByN + (size_t)c * 128 + k0 + kg * 8), acc);
#pragma unroll
    for (int r = 0; r < 4; ++r)
      ush[kg * 4 + r][ct * 16 + m16] = f2bf(acc[r] * bf2f(emv[r]));
  }
  __syncthreads();

  // S partial for this block's 256 states
  {
    const int n = tid >> 4, jg = tid & 15;
    float s = 0.f;
#pragma unroll
    for (int k = 0; k < 16; ++k) s += bf2f(ush[n][jg * 16 + k]);
    red2[tid] = s;
  }
  __syncthreads();
  if (tid < 16) {
    float S = 0.f;
#pragma unroll
    for (int j = 0; j < 16; ++j) S += red2[tid * 16 + j];
    Spart[cbuf * 256 + b * 16 + tid] = S;
  }

  // phase 3: contract
  contract256(ush, AxS2T, cb, Vpart + cbuf * 32768 + b * 2048, m16, kg, w);
}

// ---------------- finalize ----------------
__global__ __launch_bounds__(256) void k_fin2(const float* __restrict__ Spart,
                                              const float* __restrict__ Ev,
                                              const float* __restrict__ ssum,
                                              const int* __restrict__ flag,
                                              u16* __restrict__ outp) {
  __shared__ float red2[256];
  const int tid = threadIdx.x;
  red2[(tid & 15) * 16 + (tid >> 4)] = Spart[256 + tid];  // buf 1 = t=255
  __syncthreads();
  if (tid == 0) {
    float ev = 0.f;
    for (int n = 0; n < 16; ++n) {
      float S = 0.f;
      for (int j = 0; j < 16; ++j) S += red2[n * 16 + j];
      ev += Ev[n] + logf(S);
    }
    ev -= 16.0f * logf(ssum[0]);
    store_final(outp, ev, *flag);
  }
}

extern "C" void kernel_launch(void* const* d_in, const int* in_sizes, int n_in,
                              void* d_out, int out_size, void* d_ws, size_t ws_size,
                              hipStream_t stream) {
  (void)out_size;
  u16* outp = (u16*)d_out;
  if (n_in != 26 || in_sizes[25] != 128 * 256) {
    k_sentinel<<<1, 1, 0, stream>>>(outp, 5000.0f + (float)n_in);
    return;
  }
  const int* text = (const int*)d_in[0];

  char* base = (char*)d_ws;
  size_t off = 0;
  auto take = [&](size_t bytes) -> char* {
    char* p = base + off;
    off = (off + bytes + 255) & ~(size_t)255;
    return p;
  };
  int* flag = (int*)take(256);
  u16* c_se   = (u16*)take(256 * 2);
  u16* c_w[18];
  for (int i = 0; i < 18; ++i) c_w[i] = (u16*)take(((i & 1) ? 256 : 65536) * 2);
  u16* c_state = (u16*)take((size_t)1048576 * 2);
  u16* c_next  = (u16*)take((size_t)1048576 * 2);
  u16* c_pre   = (u16*)take((size_t)1048576 * 2);
  u16* c_term  = (u16*)take((size_t)8192000 * 2);
  u16* c_proj  = (u16*)take((size_t)32768 * 2);
  u16* projT  = (u16*)take(128 * 256 * 2);
  u16* twT1   = (u16*)take(65536 * 2);
  u16* twT2   = (u16*)take(65536 * 2);
  u16* twT3   = (u16*)take(65536 * 2);
  u16* twT4   = (u16*)take(65536 * 2);
  u16* ft     = (u16*)take((size_t)4096 * 256 * 2);
  float* rs_state = (float*)take(4096 * 4);
  float* rs_next  = (float*)take(4096 * 4);
  float* rs_ft    = (float*)take(4096 * 4);
  float* rs_term  = (float*)take(32000 * 4);
  u16* AxS    = (u16*)take((size_t)4096 * 128 * 2);
  u16* ByN    = (u16*)take((size_t)4096 * 128 * 2);
  u16* AxP    = (u16*)take((size_t)4096 * 128 * 2);
  u16* Btok   = (u16*)take((size_t)4096 * 128 * 2);
  u16* AxS2T  = (u16*)take((size_t)128 * 4096 * 2);
  u16* EM     = (u16*)take((size_t)4096 * 4096 * 2);
  float* SBTpart = (float*)take(500 * 128 * 4);
  float* zreg = (float*)take(2048);  // SBN[128] | SBT[128] | ssum[1] | Ev[16]
  float* SBN = zreg, *SBT = zreg + 128, *ssum = zreg + 256, *Ev = zreg + 257;
  float* recip_r   = (float*)take(4096 * 4);
  float* recip_den = (float*)take(4096 * 4);
  float* start_raw = (float*)take(4096 * 4);
  float* ex0       = (float*)take(128 * 4);
  u16* Vpart  = (u16*)take(2 * 16 * 2048 * 2);  // [2][16][16][128] bf16
  float* Spart = (float*)take(2 * 256 * 4);     // [2][16 blk][16 n]

  const float ws_mb = (float)(ws_size >> 20) > 900.f ? 900.f : (float)(ws_size >> 20);
  if (off > ws_size) {
    k_sentinel<<<1, 1, 0, stream>>>(outp, 1000.0f + ws_mb);
    return;
  }

  k_detect<<<1, 64, 0, stream>>>((const u32*)d_in[25], flag);
  k_sentinel<<<1, 1, 0, stream>>>(outp, -7777.0f);  // breadcrumb
  hipMemsetAsync(zreg, 0, 2048, stream);

  auto cvt = [&](const void* p, u16* dst, int n) {
    k_cvt<<<(n + 255) / 256, 256, 0, stream>>>((const float*)p, (const u16*)p, dst, n, flag);
  };
  cvt(d_in[2], c_se, 256);
  for (int i = 0; i < 18; ++i) cvt(d_in[3 + i], c_w[i], (i & 1) ? 256 : 65536);
  cvt(d_in[21], c_state, 1048576);
  cvt(d_in[22], c_next, 1048576);
  cvt(d_in[23], c_pre, 1048576);
  cvt(d_in[24], c_term, 8192000);
  cvt(d_in[25], c_proj, 32768);

  u16 *c_sw0 = c_w[0], *c_sb0 = c_w[1], *c_sw1 = c_w[2], *c_sb1 = c_w[3];
  u16 *c_sw2 = c_w[4], *c_sb2 = c_w[5], *c_sw3 = c_w[6], *c_sb3 = c_w[7];
  u16 *c_sw4 = c_w[8], *c_sb4 = c_w[9];
  u16 *c_tw1 = c_w[10], *c_tb1 = c_w[11], *c_tw2 = c_w[12], *c_tb2 = c_w[13];
  u16 *c_tw3 = c_w[14], *c_tb3 = c_w[15], *c_tw4 = c_w[16], *c_tb4 = c_w[17];

  k_transpose<<<128, 256, 0, stream>>>(c_proj, projT, 256, 128);
  k_transpose<<<256, 256, 0, stream>>>(c_tw1, twT1, 256, 256);
  k_transpose<<<256, 256, 0, stream>>>(c_tw2, twT2, 256, 256);
  k_transpose<<<256, 256, 0, stream>>>(c_tw3, twT3, 256, 256);
  k_transpose<<<256, 256, 0, stream>>>(c_tw4, twT4, 256, 256);
  k_start<<<1, 256, 0, stream>>>(c_se, c_sw0, c_sb0, c_sw1, c_sb1, c_sw2, c_sb2,
                                 c_sw3, c_sb3, c_sw4, c_sb4, c_proj, ex0);
  k_mlp<<<64, 256, 0, stream>>>(c_pre, twT1, c_tb1, twT2, c_tb2, twT3, c_tb3, twT4, c_tb4, ft);
  k_rownorm<<<1024, 256, 0, stream>>>(c_state, rs_state, 4096);
  k_rownorm<<<1024, 256, 0, stream>>>(c_next, rs_next, 4096);
  k_rownorm<<<1024, 256, 0, stream>>>(ft, rs_ft, 4096);
  k_rownorm<<<8000, 256, 0, stream>>>(c_term, rs_term, 32000);
  k_feat<<<64, 256, 0, stream>>>(c_state, rs_state, projT, AxS);
  k_feat<<<64, 256, 0, stream>>>(c_next, rs_next, projT, ByN);
  k_feat<<<64, 256, 0, stream>>>(ft, rs_ft, projT, AxP);
  k_feat_colsum<<<500, 256, 0, stream>>>(c_term, rs_term, projT, SBTpart);
  k_colred<<<1, 256, 0, stream>>>(SBTpart, SBT, 500);
  k_feat_gather<<<64, 256, 0, stream>>>(text, c_term, rs_term, projT, Btok);
  k_colsum<<<16, 256, 0, stream>>>(ByN, SBN, 4096);
  k_vecdots<<<1024, 256, 0, stream>>>(AxS, AxP, ByN, SBN, SBT, ex0, recip_r, recip_den,
                                      start_raw);
  k_ssum<<<1, 256, 0, stream>>>(start_raw, ssum);
  k_foldT<<<2048, 256, 0, stream>>>(AxS, recip_r, AxS2T);
  k_pair<<<dim3(32, 32), 256, 0, stream>>>(Btok, AxP, recip_den, EM);  // EM[nt][c]

  // low-rank scan: one tiny 16-block kernel per timestep
  k_vinit<<<16, 256, 0, stream>>>(EM, start_raw, AxS2T, Vpart, Spart);
  for (int t = 1; t < 256; ++t)
    k_vstep<<<16, 256, 0, stream>>>(EM, ByN, AxS2T, Vpart, Spart, Ev, t);
  k_fin2<<<1, 256, 0, stream>>>(Spart, Ev, ssum, flag, outp);
}

// Round 7
// 1886.510 us; speedup vs baseline: 4.7011x; 1.3107x over previous
//
#include <hip/hip_runtime.h>
#include <math.h>

typedef unsigned short u16;
typedef unsigned int u32;
typedef __bf16 bf16x8 __attribute__((ext_vector_type(8)));
typedef float floatx4 __attribute__((ext_vector_type(4)));

#define MFMA16(a, b, c) __builtin_amdgcn_mfma_f32_16x16x32_bf16((a), (b), (c), 0, 0, 0)

__device__ __forceinline__ float bf2f(u16 u) {
  u32 x = ((u32)u) << 16; float f; __builtin_memcpy(&f, &x, 4); return f;
}
__device__ __forceinline__ u16 f2bf(float f) {
  u32 x; __builtin_memcpy(&x, &f, 4);
  return (u16)((x + 0x7FFFu + ((x >> 16) & 1u)) >> 16);  // RNE
}
__device__ __forceinline__ void store_dual(u16* outp, float v) {
  u32 h = (u32)f2bf(v);
  *(u32*)outp = (h << 16) | h;
}
__device__ __forceinline__ bf16x8 ld8(const u16* p) { return *(const bf16x8*)p; }

__device__ __forceinline__ float wred64(float v) {
#pragma unroll
  for (int off = 32; off > 0; off >>= 1) v += __shfl_down(v, off, 64);
  return v;
}

__device__ __forceinline__ void store_final(u16* outp, float ev, int flag) {
  if (!(ev == ev) || fabsf(ev) > 1e37f) ev = -12345.0f - 1000.0f * (float)flag;
  if (flag) *(float*)outp = ev;
  else outp[0] = f2bf(ev);
}

// ---------------- diagnostics ----------------
__global__ void k_sentinel(u16* outp, float v) {
  if (threadIdx.x == 0 && blockIdx.x == 0) store_dual(outp, v);
}

// ---------------- input dtype detect: flag=1 if f32, 0 if bf16 ----------------
__global__ void k_detect(const u32* __restrict__ raw, int* __restrict__ flag) {
  if (threadIdx.x == 0 && blockIdx.x == 0) {
    int outliers = 0;
    for (int i = 0; i < 64; ++i) {
      u32 lo = raw[i] & 0xFFFFu;
      int e = (int)((lo >> 7) & 0xFF);
      if (e < 100 || e > 150) ++outliers;
    }
    *flag = (outliers > 16) ? 1 : 0;
  }
}

// ---------------- dtype-aware convert-to-bf16 ----------------
__global__ void k_cvt(const float* __restrict__ inf_, const u16* __restrict__ inb,
                      u16* __restrict__ out, int n, const int* __restrict__ flag) {
  int i = blockIdx.x * 256 + threadIdx.x;
  if (i >= n) return;
  out[i] = (*flag) ? f2bf(inf_[i]) : inb[i];
}

// ---------------- transpose (bf16), out[c][r] = in[r][c] ----------------
__global__ void k_transpose(const u16* __restrict__ in, u16* __restrict__ out, int R, int C) {
  int i = blockIdx.x * 256 + threadIdx.x;
  if (i < R * C) { int r = i / C, c = i - r * C; out[c * R + r] = in[i]; }
}

// ---------------- start-vector MLP (1 block) -> ex0[128] ----------------
__global__ __launch_bounds__(256) void k_start(
    const u16* __restrict__ se,
    const u16* __restrict__ sw0, const u16* __restrict__ sb0,
    const u16* __restrict__ sw1, const u16* __restrict__ sb1,
    const u16* __restrict__ sw2, const u16* __restrict__ sb2,
    const u16* __restrict__ sw3, const u16* __restrict__ sb3,
    const u16* __restrict__ sw4, const u16* __restrict__ sb4,
    const u16* __restrict__ proj, float* __restrict__ ex0) {
  __shared__ float xa[256], xb[256], xc[256], red[256];
  const int tid = threadIdx.x;
  xa[tid] = bf2f(se[tid]);
  __syncthreads();
  float acc = bf2f(sb0[tid]);
  for (int k = 0; k < 256; ++k) acc += xa[k] * bf2f(sw0[k * 256 + tid]);
  xb[tid] = acc;  // f0 (Linear, no relu)
  __syncthreads();
  acc = bf2f(sb1[tid]);
  for (int k = 0; k < 256; ++k) acc += xb[k] * bf2f(sw1[k * 256 + tid]);
  xc[tid] = fmaxf(acc, 0.f);
  __syncthreads();
  acc = bf2f(sb2[tid]);
  for (int k = 0; k < 256; ++k) acc += xc[k] * bf2f(sw2[k * 256 + tid]);
  xa[tid] = fmaxf(acc, 0.f) + xb[tid];  // f1
  __syncthreads();
  acc = bf2f(sb3[tid]);
  for (int k = 0; k < 256; ++k) acc += xa[k] * bf2f(sw3[k * 256 + tid]);
  xc[tid] = fmaxf(acc, 0.f);
  __syncthreads();
  acc = bf2f(sb4[tid]);
  for (int k = 0; k < 256; ++k) acc += xc[k] * bf2f(sw4[k * 256 + tid]);
  xb[tid] = fmaxf(acc, 0.f) + xa[tid];  // f2
  __syncthreads();
  red[tid] = xb[tid] * xb[tid];
  __syncthreads();
  for (int s = 128; s > 0; s >>= 1) {
    if (tid < s) red[tid] += red[tid + s];
    __syncthreads();
  }
  const float rs = rsqrtf(red[0]);
  xa[tid] = xb[tid] * rs;
  __syncthreads();
  if (tid < 128) {
    float a = 0.f;
    for (int k = 0; k < 256; ++k) a += xa[k] * bf2f(proj[k * 128 + tid]);
    ex0[tid] = expf(a);
  }
}

// ---------------- preterminal MLP: ft = res(res(X0)) via MFMA ----------------
__global__ __launch_bounds__(256) void k_mlp(
    const u16* __restrict__ X0,
    const u16* __restrict__ w1T, const u16* __restrict__ b1,
    const u16* __restrict__ w2T, const u16* __restrict__ b2,
    const u16* __restrict__ w3T, const u16* __restrict__ b3,
    const u16* __restrict__ w4T, const u16* __restrict__ b4,
    u16* __restrict__ FT) {
  __shared__ __align__(16) u16 Y[2][64][264];
  const int tid = threadIdx.x, lane = tid & 63, w = tid >> 6;
  const int m16 = lane & 15, kg = lane >> 4;
  const int rbl = w * 16;
  const int rbg = blockIdx.x * 64 + rbl;
  const floatx4 z4 = {0.f, 0.f, 0.f, 0.f};
  floatx4 acc[16];

#pragma unroll
  for (int ct = 0; ct < 16; ++ct) acc[ct] = z4;
  for (int k0 = 0; k0 < 256; k0 += 32) {
    bf16x8 a = ld8(X0 + (size_t)(rbg + m16) * 256 + k0 + kg * 8);
#pragma unroll
    for (int ct = 0; ct < 16; ++ct)
      acc[ct] = MFMA16(a, ld8(w1T + (ct * 16 + m16) * 256 + k0 + kg * 8), acc[ct]);
  }
#pragma unroll
  for (int ct = 0; ct < 16; ++ct) {
    const int col = ct * 16 + m16;
    const float bv = bf2f(b1[col]);
#pragma unroll
    for (int r = 0; r < 4; ++r)
      Y[0][rbl + kg * 4 + r][col] = f2bf(fmaxf(acc[ct][r] + bv, 0.f));
  }
  __syncthreads();
#pragma unroll
  for (int ct = 0; ct < 16; ++ct) acc[ct] = z4;
  for (int k0 = 0; k0 < 256; k0 += 32) {
    bf16x8 a = *(const bf16x8*)(&Y[0][rbl + m16][k0 + kg * 8]);
#pragma unroll
    for (int ct = 0; ct < 16; ++ct)
      acc[ct] = MFMA16(a, ld8(w2T + (ct * 16 + m16) * 256 + k0 + kg * 8), acc[ct]);
  }
#pragma unroll
  for (int ct = 0; ct < 16; ++ct) {
    const int col = ct * 16 + m16;
    const float bv = bf2f(b2[col]);
#pragma unroll
    for (int r = 0; r < 4; ++r) {
      const int gr = rbg + kg * 4 + r;
      float v = fmaxf(acc[ct][r] + bv, 0.f) + bf2f(X0[(size_t)gr * 256 + col]);
      Y[1][rbl + kg * 4 + r][col] = f2bf(v);
    }
  }
  __syncthreads();
#pragma unroll
  for (int ct = 0; ct < 16; ++ct) acc[ct] = z4;
  for (int k0 = 0; k0 < 256; k0 += 32) {
    bf16x8 a = *(const bf16x8*)(&Y[1][rbl + m16][k0 + kg * 8]);
#pragma unroll
    for (int ct = 0; ct < 16; ++ct)
      acc[ct] = MFMA16(a, ld8(w3T + (ct * 16 + m16) * 256 + k0 + kg * 8), acc[ct]);
  }
#pragma unroll
  for (int ct = 0; ct < 16; ++ct) {
    const int col = ct * 16 + m16;
    const float bv = bf2f(b3[col]);
#pragma unroll
    for (int r = 0; r < 4; ++r)
      Y[0][rbl + kg * 4 + r][col] = f2bf(fmaxf(acc[ct][r] + bv, 0.f));
  }
  __syncthreads();
#pragma unroll
  for (int ct = 0; ct < 16; ++ct) acc[ct] = z4;
  for (int k0 = 0; k0 < 256; k0 += 32) {
    bf16x8 a = *(const bf16x8*)(&Y[0][rbl + m16][k0 + kg * 8]);
#pragma unroll
    for (int ct = 0; ct < 16; ++ct)
      acc[ct] = MFMA16(a, ld8(w4T + (ct * 16 + m16) * 256 + k0 + kg * 8), acc[ct]);
  }
#pragma unroll
  for (int ct = 0; ct < 16; ++ct) {
    const int col = ct * 16 + m16;
    const float bv = bf2f(b4[col]);
#pragma unroll
    for (int r = 0; r < 4; ++r) {
      const int rl = rbl + kg * 4 + r;
      float v = fmaxf(acc[ct][r] + bv, 0.f) + bf2f(Y[1][rl][col]);
      FT[(size_t)(rbg + kg * 4 + r) * 256 + col] = f2bf(v);
    }
  }
}

// ---------------- per-row 1/||x|| over 256 cols ----------------
__global__ __launch_bounds__(256) void k_rownorm(const u16* __restrict__ X,
                                                 float* __restrict__ rscale, int rows) {
  const int w = threadIdx.x >> 6, lane = threadIdx.x & 63;
  const int row = blockIdx.x * 4 + w;
  if (row >= rows) return;
  const u16* p = X + (size_t)row * 256 + lane * 4;
  float s = 0.f;
#pragma unroll
  for (int i = 0; i < 4; ++i) { float v = bf2f(p[i]); s += v * v; }
  s = wred64(s);
  if (lane == 0) rscale[row] = rsqrtf(s);
}

// ---------------- features: OUT[r][d] = exp(rscale[r] * X[r]·projT[d]) ----------------
__global__ __launch_bounds__(256) void k_feat(const u16* __restrict__ X,
                                              const float* __restrict__ rscale,
                                              const u16* __restrict__ PT,
                                              u16* __restrict__ OUT) {
  const int tid = threadIdx.x, lane = tid & 63, w = tid >> 6;
  const int m16 = lane & 15, kg = lane >> 4;
  const int rb = blockIdx.x * 64 + w * 16;
  const floatx4 z4 = {0.f, 0.f, 0.f, 0.f};
  floatx4 acc[8];
#pragma unroll
  for (int ct = 0; ct < 8; ++ct) acc[ct] = z4;
  for (int k0 = 0; k0 < 256; k0 += 32) {
    bf16x8 a = ld8(X + (size_t)(rb + m16) * 256 + k0 + kg * 8);
#pragma unroll
    for (int ct = 0; ct < 8; ++ct)
      acc[ct] = MFMA16(a, ld8(PT + (ct * 16 + m16) * 256 + k0 + kg * 8), acc[ct]);
  }
  float rs[4];
#pragma unroll
  for (int r = 0; r < 4; ++r) rs[r] = rscale[rb + kg * 4 + r];
#pragma unroll
  for (int ct = 0; ct < 8; ++ct)
#pragma unroll
    for (int r = 0; r < 4; ++r)
      OUT[(size_t)(rb + kg * 4 + r) * 128 + ct * 16 + m16] = f2bf(expf(acc[ct][r] * rs[r]));
}

// ---------------- term features fused with column-sum ----------------
__global__ __launch_bounds__(256) void k_feat_colsum(const u16* __restrict__ X,
                                                     const float* __restrict__ rscale,
                                                     const u16* __restrict__ PT,
                                                     float* __restrict__ part) {
  __shared__ float cred[128];
  const int tid = threadIdx.x, lane = tid & 63, w = tid >> 6;
  const int m16 = lane & 15, kg = lane >> 4;
  const int rb = blockIdx.x * 64 + w * 16;
  if (tid < 128) cred[tid] = 0.f;
  __syncthreads();
  const floatx4 z4 = {0.f, 0.f, 0.f, 0.f};
  floatx4 acc[8];
#pragma unroll
  for (int ct = 0; ct < 8; ++ct) acc[ct] = z4;
  for (int k0 = 0; k0 < 256; k0 += 32) {
    bf16x8 a = ld8(X + (size_t)(rb + m16) * 256 + k0 + kg * 8);
#pragma unroll
    for (int ct = 0; ct < 8; ++ct)
      acc[ct] = MFMA16(a, ld8(PT + (ct * 16 + m16) * 256 + k0 + kg * 8), acc[ct]);
  }
  float rs[4];
#pragma unroll
  for (int r = 0; r < 4; ++r) rs[r] = rscale[rb + kg * 4 + r];
#pragma unroll
  for (int ct = 0; ct < 8; ++ct) {
    float s = 0.f;
#pragma unroll
    for (int r = 0; r < 4; ++r) s += expf(acc[ct][r] * rs[r]);
    atomicAdd(&cred[ct * 16 + m16], s);
  }
  __syncthreads();
  if (tid < 128) part[(size_t)blockIdx.x * 128 + tid] = cred[tid];
}

__global__ void k_colred(const float* __restrict__ part, float* __restrict__ out, int nblk) {
  const int tid = threadIdx.x;
  if (tid < 128) {
    float s = 0.f;
    for (int b = 0; b < nblk; ++b) s += part[(size_t)b * 128 + tid];
    out[tid] = s;
  }
}

// ---------------- gathered token features ----------------
__global__ __launch_bounds__(256) void k_feat_gather(const int* __restrict__ text,
                                                     const u16* __restrict__ TE,
                                                     const float* __restrict__ rs_term,
                                                     const u16* __restrict__ PT,
                                                     u16* __restrict__ Btok) {
  const int tid = threadIdx.x, lane = tid & 63, w = tid >> 6;
  const int m16 = lane & 15, kg = lane >> 4;
  const int rb = blockIdx.x * 64 + w * 16;
  const int ia = rb + m16;
  const int tok_a = text[(ia & 15) * 256 + (ia >> 4)];
  const floatx4 z4 = {0.f, 0.f, 0.f, 0.f};
  floatx4 acc[8];
#pragma unroll
  for (int ct = 0; ct < 8; ++ct) acc[ct] = z4;
  for (int k0 = 0; k0 < 256; k0 += 32) {
    bf16x8 a = ld8(TE + (size_t)tok_a * 256 + k0 + kg * 8);
#pragma unroll
    for (int ct = 0; ct < 8; ++ct)
      acc[ct] = MFMA16(a, ld8(PT + (ct * 16 + m16) * 256 + k0 + kg * 8), acc[ct]);
  }
  float rs[4];
#pragma unroll
  for (int r = 0; r < 4; ++r) {
    const int io = rb + kg * 4 + r;
    rs[r] = rs_term[text[(io & 15) * 256 + (io >> 4)]];
  }
#pragma unroll
  for (int ct = 0; ct < 8; ++ct)
#pragma unroll
    for (int r = 0; r < 4; ++r)
      Btok[(size_t)(rb + kg * 4 + r) * 128 + ct * 16 + m16] = f2bf(expf(acc[ct][r] * rs[r]));
}

// ---------------- colsum (ByN -> SBN) ----------------
__global__ __launch_bounds__(256) void k_colsum(const u16* __restrict__ X,
                                                float* __restrict__ out, int rows) {
  __shared__ float red[256];
  const int tid = threadIdx.x, d = tid & 127, g = tid >> 7;
  const int r0 = blockIdx.x * 256 + g, r1 = blockIdx.x * 256 + 256;
  float s = 0.f;
  for (int r = r0; r < r1; r += 2) s += bf2f(X[(size_t)r * 128 + d]);
  red[tid] = s;
  __syncthreads();
  if (tid < 128) atomicAdd(out + tid, red[tid] + red[tid + 128]);
}

// ---------------- per-state scalars ----------------
__global__ __launch_bounds__(256) void k_vecdots(
    const u16* __restrict__ AxS, const u16* __restrict__ AxP, const u16* __restrict__ ByN,
    const float* __restrict__ SBN, const float* __restrict__ SBT, const float* __restrict__ ex0,
    float* __restrict__ recip_r, float* __restrict__ recip_den,
    float* __restrict__ start_raw) {
  const int w = threadIdx.x >> 6, lane = threadIdx.x & 63;
  const int c = blockIdx.x * 4 + w;
  const int d = lane * 2;
  float a0 = bf2f(AxS[(size_t)c * 128 + d]), a1 = bf2f(AxS[(size_t)c * 128 + d + 1]);
  float t = wred64(a0 * SBN[d] + a1 * SBN[d + 1]);
  float p0 = bf2f(AxP[(size_t)c * 128 + d]), p1 = bf2f(AxP[(size_t)c * 128 + d + 1]);
  float p = wred64(p0 * SBT[d] + p1 * SBT[d + 1]);
  float y0 = bf2f(ByN[(size_t)c * 128 + d]), y1 = bf2f(ByN[(size_t)c * 128 + d + 1]);
  float s = wred64(y0 * ex0[d] + y1 * ex0[d + 1]);
  if (lane == 0) {
    recip_r[c] = 1.0f / t;
    recip_den[c] = 1.0f / p;
    start_raw[c] = s;
  }
}

__global__ void k_ssum(const float* __restrict__ start_raw, float* __restrict__ ssum) {
  __shared__ float red[256];
  const int tid = threadIdx.x;
  float s = 0.f;
  for (int i = tid; i < 4096; i += 256) s += start_raw[i];
  red[tid] = s;
  __syncthreads();
  for (int st = 128; st > 0; st >>= 1) {
    if (tid < st) red[tid] += red[tid + st];
    __syncthreads();
  }
  if (tid == 0) ssum[0] = red[0];
}

// ---------------- AxS2T[d][c] = AxS[c][d] * recip_r[c]  ([128 x 4096] bf16) ----------------
__global__ void k_foldT(const u16* __restrict__ AxS, const float* __restrict__ recip_r,
                        u16* __restrict__ AxS2T) {
  int i = blockIdx.x * 256 + threadIdx.x;  // 128*4096
  if (i >= 128 * 4096) return;
  int d = i >> 12, c = i & 4095;
  AxS2T[i] = f2bf(bf2f(AxS[(size_t)c * 128 + d]) * recip_r[c]);
}

// ---------------- EM[nt][c] = (A[nt]·B[c]) * cscale[c], K=128 ----------------
__global__ __launch_bounds__(256) void k_pair(const u16* __restrict__ A, const u16* __restrict__ B,
                                              const float* __restrict__ cscale,
                                              u16* __restrict__ OUT) {
  const int tid = threadIdx.x, lane = tid & 63, w = tid >> 6;
  const int m16 = lane & 15, kg = lane >> 4;
  const int mb = blockIdx.y * 128 + w * 32;
  const int nb = blockIdx.x * 128;
  const floatx4 z4 = {0.f, 0.f, 0.f, 0.f};
  floatx4 acc[2][8];
#pragma unroll
  for (int rt = 0; rt < 2; ++rt)
#pragma unroll
    for (int ct = 0; ct < 8; ++ct) acc[rt][ct] = z4;
  for (int k0 = 0; k0 < 128; k0 += 32) {
    bf16x8 a0 = ld8(A + (size_t)(mb + m16) * 128 + k0 + kg * 8);
    bf16x8 a1 = ld8(A + (size_t)(mb + 16 + m16) * 128 + k0 + kg * 8);
#pragma unroll
    for (int ct = 0; ct < 8; ++ct) {
      bf16x8 bb = ld8(B + (size_t)(nb + ct * 16 + m16) * 128 + k0 + kg * 8);
      acc[0][ct] = MFMA16(a0, bb, acc[0][ct]);
      acc[1][ct] = MFMA16(a1, bb, acc[1][ct]);
    }
  }
  float cs[8];
#pragma unroll
  for (int ct = 0; ct < 8; ++ct) cs[ct] = cscale[nb + ct * 16 + m16];
#pragma unroll
  for (int rt = 0; rt < 2; ++rt)
#pragma unroll
    for (int ct = 0; ct < 8; ++ct)
#pragma unroll
      for (int r = 0; r < 4; ++r)
        OUT[(size_t)(mb + rt * 16 + kg * 4 + r) * 4096 + nb + ct * 16 + m16] =
            f2bf(acc[rt][ct][r] * cs[ct]);
}

// ---------------- persistent 16-block scan with LLC atomic barrier ----------------
// Vacc[t][n][d] f32, Sacc[t][n] f32, cnt[t] u32 -- all write-once per t, zeroed per call.
__global__ __launch_bounds__(256) void k_scan(
    const u16* __restrict__ EM, const u16* __restrict__ ByN, const u16* __restrict__ AxS2T,
    const float* __restrict__ start_raw, const float* __restrict__ ssum,
    float* __restrict__ Vacc, float* __restrict__ Sacc, u32* __restrict__ cnt,
    const int* __restrict__ flag, u16* __restrict__ outp) {
  __shared__ __align__(16) u16 ByNs[256][132];   // [c_local][d]
  __shared__ __align__(16) u16 AxS2s[128][260];  // [e][c_local]
  __shared__ __align__(16) u16 ush[16][264];     // [n][c_local]
  __shared__ __align__(16) u16 vsh[16][136];     // [n][d]
  __shared__ float red2[256];
  __shared__ float recipS[16];
  __shared__ float finred[16];
  __shared__ int timeout_sh;
  const int tid = threadIdx.x, lane = tid & 63, w = tid >> 6;
  const int m16 = lane & 15, kg = lane >> 4;
  const int b = blockIdx.x, cb = b * 256;
  const floatx4 z4 = {0.f, 0.f, 0.f, 0.f};
  float evreg = 0.f;  // valid for b==0 && tid<16

  if (tid == 0) timeout_sh = 0;
  // stage ByN slice [256][128]
  for (int i = tid; i < 4096; i += 256) {
    const int r = i >> 4, c8 = (i & 15) * 8;
    *(uint4*)(&ByNs[r][c8]) = *(const uint4*)(ByN + (size_t)(cb + r) * 128 + c8);
  }
  // stage AxS2T slice [128][256]
  for (int i = tid; i < 4096; i += 256) {
    const int e = i >> 5, c8 = (i & 31) * 8;
    *(uint4*)(&AxS2s[e][c8]) = *(const uint4*)(AxS2T + (size_t)e * 4096 + cb + c8);
  }
  __syncthreads();

  // ---- t = 0: u0 = start_raw * EM[0] ----
  {
    const int n0 = tid >> 4, cg0 = tid & 15;
    float s0 = 0.f;
#pragma unroll
    for (int j = 0; j < 16; ++j) {
      const int c = cg0 * 16 + j;
      float u = start_raw[cb + c] * bf2f(EM[(size_t)n0 * 4096 + cb + c]);
      ush[n0][c] = f2bf(u);
      s0 += u;
    }
    red2[tid] = s0;
  }
  __syncthreads();
  if (tid < 16) {
    float S = 0.f;
#pragma unroll
    for (int j = 0; j < 16; ++j) S += red2[tid * 16 + j];
    atomicAdd(&Sacc[tid], S);
  }
  // contract u0 -> Vacc[0]
#pragma unroll
  for (int ct2 = 0; ct2 < 2; ++ct2) {
    const int ct = w * 2 + ct2;
    floatx4 acc = z4;
#pragma unroll
    for (int k0 = 0; k0 < 256; k0 += 32)
      acc = MFMA16(*(const bf16x8*)(&ush[m16][k0 + kg * 8]),
                   *(const bf16x8*)(&AxS2s[ct * 16 + m16][k0 + kg * 8]), acc);
#pragma unroll
    for (int r = 0; r < 4; ++r)
      atomicAdd(&Vacc[(size_t)(kg * 4 + r) * 128 + ct * 16 + m16], acc[r]);
  }
  __threadfence();
  __syncthreads();
  if (tid == 0)
    __hip_atomic_fetch_add(&cnt[0], 1u, __ATOMIC_RELEASE, __HIP_MEMORY_SCOPE_AGENT);

  // ---- main loop ----
  for (int t = 1; t < 256; ++t) {
    // prefetch EM tile for this step into registers (overlaps the spin)
    u16 emv[4][4];
#pragma unroll
    for (int ct2 = 0; ct2 < 4; ++ct2) {
      const int c = cb + (w * 4 + ct2) * 16 + m16;
#pragma unroll
      for (int r = 0; r < 4; ++r)
        emv[ct2][r] = EM[(size_t)(t * 16 + kg * 4 + r) * 4096 + c];
    }
    // barrier: wait for all 16 blocks to finish step t-1
    if (tid == 0) {
      long it = 0;
      while (__hip_atomic_load(&cnt[t - 1], __ATOMIC_ACQUIRE, __HIP_MEMORY_SCOPE_AGENT) < 16u) {
        if (++it > 50000000L) { timeout_sh = 1; break; }
      }
    }
    __syncthreads();
    if (timeout_sh) break;
    // read S_{t-1}, v_{t-1}
    if (tid < 16) {
      float S = __hip_atomic_load(&Sacc[(t - 1) * 16 + tid], __ATOMIC_RELAXED,
                                  __HIP_MEMORY_SCOPE_AGENT);
      recipS[tid] = 1.0f / S;
      if (b == 0) evreg += logf(S);
    }
    float vv[8];
    const int n1 = tid >> 4, d8 = (tid & 15) * 8;
    {
      const float* vp = Vacc + (size_t)((t - 1) * 16 + n1) * 128 + d8;
#pragma unroll
      for (int j = 0; j < 8; ++j)
        vv[j] = __hip_atomic_load(vp + j, __ATOMIC_RELAXED, __HIP_MEMORY_SCOPE_AGENT);
    }
    __syncthreads();
    {
      const float rS = recipS[n1];
      u16 tmp[8];
#pragma unroll
      for (int j = 0; j < 8; ++j) tmp[j] = f2bf(vv[j] * rS);
      *(uint4*)(&vsh[n1][d8]) = *(uint4*)tmp;
    }
    __syncthreads();
    // expand: u[n][c] = (v·ByN[c]) * EM[t][n][c]
#pragma unroll
    for (int ct2 = 0; ct2 < 4; ++ct2) {
      const int ct = w * 4 + ct2;
      floatx4 acc = z4;
#pragma unroll
      for (int k0 = 0; k0 < 128; k0 += 32)
        acc = MFMA16(*(const bf16x8*)(&vsh[m16][k0 + kg * 8]),
                     *(const bf16x8*)(&ByNs[ct * 16 + m16][k0 + kg * 8]), acc);
#pragma unroll
      for (int r = 0; r < 4; ++r)
        ush[kg * 4 + r][ct * 16 + m16] = f2bf(acc[r] * bf2f(emv[ct2][r]));
    }
    __syncthreads();
    // S partial
    {
      const int n = tid >> 4, jg = tid & 15;
      float s = 0.f;
#pragma unroll
      for (int k = 0; k < 16; ++k) s += bf2f(ush[n][jg * 16 + k]);
      red2[tid] = s;
    }
    __syncthreads();
    if (tid < 16) {
      float S = 0.f;
#pragma unroll
      for (int j = 0; j < 16; ++j) S += red2[tid * 16 + j];
      atomicAdd(&Sacc[t * 16 + tid], S);
    }
    // contract -> Vacc[t]
#pragma unroll
    for (int ct2 = 0; ct2 < 2; ++ct2) {
      const int ct = w * 2 + ct2;
      floatx4 acc = z4;
#pragma unroll
      for (int k0 = 0; k0 < 256; k0 += 32)
        acc = MFMA16(*(const bf16x8*)(&ush[m16][k0 + kg * 8]),
                     *(const bf16x8*)(&AxS2s[ct * 16 + m16][k0 + kg * 8]), acc);
#pragma unroll
      for (int r = 0; r < 4; ++r)
        atomicAdd(&Vacc[(size_t)(t * 16 + kg * 4 + r) * 128 + ct * 16 + m16], acc[r]);
    }
    __threadfence();
    __syncthreads();
    if (tid == 0)
      __hip_atomic_fetch_add(&cnt[t], 1u, __ATOMIC_RELEASE, __HIP_MEMORY_SCOPE_AGENT);
  }

  // ---- finalize (block 0) ----
  if (b == 0) {
    if (tid == 0 && !timeout_sh) {
      long it = 0;
      while (__hip_atomic_load(&cnt[255], __ATOMIC_ACQUIRE, __HIP_MEMORY_SCOPE_AGENT) < 16u) {
        if (++it > 50000000L) { timeout_sh = 1; break; }
      }
    }
    __syncthreads();
    if (tid < 16) {
      float S = __hip_atomic_load(&Sacc[255 * 16 + tid], __ATOMIC_RELAXED,
                                  __HIP_MEMORY_SCOPE_AGENT);
      finred[tid] = evreg + logf(S);
    }
    __syncthreads();
    if (tid == 0) {
      float ev = 0.f;
      for (int i = 0; i < 16; ++i) ev += finred[i];
      ev -= 16.0f * logf(ssum[0]);
      if (timeout_sh) ev = -66666.0f;
      store_final(outp, ev, *flag);
    }
  }
}

extern "C" void kernel_launch(void* const* d_in, const int* in_sizes, int n_in,
                              void* d_out, int out_size, void* d_ws, size_t ws_size,
                              hipStream_t stream) {
  (void)out_size;
  u16* outp = (u16*)d_out;
  if (n_in != 26 || in_sizes[25] != 128 * 256) {
    k_sentinel<<<1, 1, 0, stream>>>(outp, 5000.0f + (float)n_in);
    return;
  }
  const int* text = (const int*)d_in[0];

  char* base = (char*)d_ws;
  size_t off = 0;
  auto take = [&](size_t bytes) -> char* {
    char* p = base + off;
    off = (off + bytes + 255) & ~(size_t)255;
    return p;
  };
  int* flag = (int*)take(256);
  u16* c_se   = (u16*)take(256 * 2);
  u16* c_w[18];
  for (int i = 0; i < 18; ++i) c_w[i] = (u16*)take(((i & 1) ? 256 : 65536) * 2);
  u16* c_state = (u16*)take((size_t)1048576 * 2);
  u16* c_next  = (u16*)take((size_t)1048576 * 2);
  u16* c_pre   = (u16*)take((size_t)1048576 * 2);
  u16* c_term  = (u16*)take((size_t)8192000 * 2);
  u16* c_proj  = (u16*)take((size_t)32768 * 2);
  u16* projT  = (u16*)take(128 * 256 * 2);
  u16* twT1   = (u16*)take(65536 * 2);
  u16* twT2   = (u16*)take(65536 * 2);
  u16* twT3   = (u16*)take(65536 * 2);
  u16* twT4   = (u16*)take(65536 * 2);
  u16* ft     = (u16*)take((size_t)4096 * 256 * 2);
  float* rs_state = (float*)take(4096 * 4);
  float* rs_next  = (float*)take(4096 * 4);
  float* rs_ft    = (float*)take(4096 * 4);
  float* rs_term  = (float*)take(32000 * 4);
  u16* AxS    = (u16*)take((size_t)4096 * 128 * 2);
  u16* ByN    = (u16*)take((size_t)4096 * 128 * 2);
  u16* AxP    = (u16*)take((size_t)4096 * 128 * 2);
  u16* Btok   = (u16*)take((size_t)4096 * 128 * 2);
  u16* AxS2T  = (u16*)take((size_t)128 * 4096 * 2);
  u16* EM     = (u16*)take((size_t)4096 * 4096 * 2);
  float* SBTpart = (float*)take(500 * 128 * 4);
  float* zreg = (float*)take(2048);  // SBN[128] | SBT[128] | ssum[1]
  float* SBN = zreg, *SBT = zreg + 128, *ssum = zreg + 256;
  float* recip_r   = (float*)take(4096 * 4);
  float* recip_den = (float*)take(4096 * 4);
  float* start_raw = (float*)take(4096 * 4);
  float* ex0       = (float*)take(128 * 4);
  // barrier region (zeroed every call): cnt[256] | Sacc[256][16] | Vacc[256][16][128]
  char* barr = take(1024 + 16384 + (size_t)256 * 16 * 128 * 4);
  u32* cnt   = (u32*)barr;
  float* Sacc = (float*)(barr + 1024);
  float* Vacc = (float*)(barr + 1024 + 16384);

  const float ws_mb = (float)(ws_size >> 20) > 900.f ? 900.f : (float)(ws_size >> 20);
  if (off > ws_size) {
    k_sentinel<<<1, 1, 0, stream>>>(outp, 1000.0f + ws_mb);
    return;
  }

  k_detect<<<1, 64, 0, stream>>>((const u32*)d_in[25], flag);
  k_sentinel<<<1, 1, 0, stream>>>(outp, -7777.0f);  // breadcrumb
  hipMemsetAsync(zreg, 0, 2048, stream);
  hipMemsetAsync(barr, 0, 1024 + 16384 + (size_t)256 * 16 * 128 * 4, stream);

  auto cvt = [&](const void* p, u16* dst, int n) {
    k_cvt<<<(n + 255) / 256, 256, 0, stream>>>((const float*)p, (const u16*)p, dst, n, flag);
  };
  cvt(d_in[2], c_se, 256);
  for (int i = 0; i < 18; ++i) cvt(d_in[3 + i], c_w[i], (i & 1) ? 256 : 65536);
  cvt(d_in[21], c_state, 1048576);
  cvt(d_in[22], c_next, 1048576);
  cvt(d_in[23], c_pre, 1048576);
  cvt(d_in[24], c_term, 8192000);
  cvt(d_in[25], c_proj, 32768);

  u16 *c_sw0 = c_w[0], *c_sb0 = c_w[1], *c_sw1 = c_w[2], *c_sb1 = c_w[3];
  u16 *c_sw2 = c_w[4], *c_sb2 = c_w[5], *c_sw3 = c_w[6], *c_sb3 = c_w[7];
  u16 *c_sw4 = c_w[8], *c_sb4 = c_w[9];
  u16 *c_tw1 = c_w[10], *c_tb1 = c_w[11], *c_tw2 = c_w[12], *c_tb2 = c_w[13];
  u16 *c_tw3 = c_w[14], *c_tb3 = c_w[15], *c_tw4 = c_w[16], *c_tb4 = c_w[17];

  k_transpose<<<128, 256, 0, stream>>>(c_proj, projT, 256, 128);
  k_transpose<<<256, 256, 0, stream>>>(c_tw1, twT1, 256, 256);
  k_transpose<<<256, 256, 0, stream>>>(c_tw2, twT2, 256, 256);
  k_transpose<<<256, 256, 0, stream>>>(c_tw3, twT3, 256, 256);
  k_transpose<<<256, 256, 0, stream>>>(c_tw4, twT4, 256, 256);
  k_start<<<1, 256, 0, stream>>>(c_se, c_sw0, c_sb0, c_sw1, c_sb1, c_sw2, c_sb2,
                                 c_sw3, c_sb3, c_sw4, c_sb4, c_proj, ex0);
  k_mlp<<<64, 256, 0, stream>>>(c_pre, twT1, c_tb1, twT2, c_tb2, twT3, c_tb3, twT4, c_tb4, ft);
  k_rownorm<<<1024, 256, 0, stream>>>(c_state, rs_state, 4096);
  k_rownorm<<<1024, 256, 0, stream>>>(c_next, rs_next, 4096);
  k_rownorm<<<1024, 256, 0, stream>>>(ft, rs_ft, 4096);
  k_rownorm<<<8000, 256, 0, stream>>>(c_term, rs_term, 32000);
  k_feat<<<64, 256, 0, stream>>>(c_state, rs_state, projT, AxS);
  k_feat<<<64, 256, 0, stream>>>(c_next, rs_next, projT, ByN);
  k_feat<<<64, 256, 0, stream>>>(ft, rs_ft, projT, AxP);
  k_feat_colsum<<<500, 256, 0, stream>>>(c_term, rs_term, projT, SBTpart);
  k_colred<<<1, 256, 0, stream>>>(SBTpart, SBT, 500);
  k_feat_gather<<<64, 256, 0, stream>>>(text, c_term, rs_term, projT, Btok);
  k_colsum<<<16, 256, 0, stream>>>(ByN, SBN, 4096);
  k_vecdots<<<1024, 256, 0, stream>>>(AxS, AxP, ByN, SBN, SBT, ex0, recip_r, recip_den,
                                      start_raw);
  k_ssum<<<1, 256, 0, stream>>>(start_raw, ssum);
  k_foldT<<<2048, 256, 0, stream>>>(AxS, recip_r, AxS2T);
  k_pair<<<dim3(32, 32), 256, 0, stream>>>(Btok, AxP, recip_den, EM);  // EM[nt][c]

  // single persistent scan kernel: 16 blocks, LLC atomic barrier per step
  k_scan<<<16, 256, 0, stream>>>(EM, ByN, AxS2T, start_raw, ssum, Vacc, Sacc, cnt, flag, outp);
}

// Round 8
// 1818.695 us; speedup vs baseline: 4.8763x; 1.0373x over previous
//
#include <hip/hip_runtime.h>
#include <math.h>

typedef unsigned short u16;
typedef unsigned int u32;
typedef __bf16 bf16x8 __attribute__((ext_vector_type(8)));
typedef float floatx4 __attribute__((ext_vector_type(4)));

#define MFMA16(a, b, c) __builtin_amdgcn_mfma_f32_16x16x32_bf16((a), (b), (c), 0, 0, 0)

__device__ __forceinline__ float bf2f(u16 u) {
  u32 x = ((u32)u) << 16; float f; __builtin_memcpy(&f, &x, 4); return f;
}
__device__ __forceinline__ u16 f2bf(float f) {
  u32 x; __builtin_memcpy(&x, &f, 4);
  return (u16)((x + 0x7FFFu + ((x >> 16) & 1u)) >> 16);  // RNE
}
__device__ __forceinline__ void store_dual(u16* outp, float v) {
  u32 h = (u32)f2bf(v);
  *(u32*)outp = (h << 16) | h;
}
__device__ __forceinline__ bf16x8 ld8(const u16* p) { return *(const bf16x8*)p; }

__device__ __forceinline__ float wred64(float v) {
#pragma unroll
  for (int off = 32; off > 0; off >>= 1) v += __shfl_down(v, off, 64);
  return v;
}

__device__ __forceinline__ void store_final(u16* outp, float ev, int flag) {
  if (!(ev == ev) || fabsf(ev) > 1e37f) ev = -12345.0f - 1000.0f * (float)flag;
  if (flag) *(float*)outp = ev;
  else outp[0] = f2bf(ev);
}

// ---------------- diagnostics ----------------
__global__ void k_sentinel(u16* outp, float v) {
  if (threadIdx.x == 0 && blockIdx.x == 0) store_dual(outp, v);
}

// ---------------- input dtype detect: flag=1 if f32, 0 if bf16 ----------------
__global__ void k_detect(const u32* __restrict__ raw, int* __restrict__ flag) {
  if (threadIdx.x == 0 && blockIdx.x == 0) {
    int outliers = 0;
    for (int i = 0; i < 64; ++i) {
      u32 lo = raw[i] & 0xFFFFu;
      int e = (int)((lo >> 7) & 0xFF);
      if (e < 100 || e > 150) ++outliers;
    }
    *flag = (outliers > 16) ? 1 : 0;
  }
}

// ---------------- fused dtype-aware convert (24 jobs, one launch) ----------------
struct CvtJobs {
  const void* src[24];
  u16* dst[24];
  int n[24];
  int bstart[25];
};
__global__ __launch_bounds__(256) void k_cvt_all(CvtJobs a, const int* __restrict__ flag) {
  const int b = blockIdx.x, tid = threadIdx.x;
  int j = 0;
  while (b >= a.bstart[j + 1]) ++j;
  const int base = (b - a.bstart[j]) * 4096;
  const int n = a.n[j];
  if (*flag) {
    const float* s = (const float*)a.src[j];
    u16* d = a.dst[j];
    for (int i0 = base + tid * 4; i0 < base + 4096 && i0 < n; i0 += 1024) {
      float4 v = *(const float4*)(s + i0);
      u16 o[4] = {f2bf(v.x), f2bf(v.y), f2bf(v.z), f2bf(v.w)};
      __builtin_memcpy(d + i0, o, 8);
    }
  } else {
    const u16* s = (const u16*)a.src[j];
    u16* d = a.dst[j];
    for (int i0 = base + tid * 4; i0 < base + 4096 && i0 < n; i0 += 1024)
      *(uint2*)(d + i0) = *(const uint2*)(s + i0);
  }
}

// ---------------- fused transpose (5 jobs) ----------------
struct TrJobs {
  const u16* src[5];
  u16* dst[5];
  int R[5], C[5];
  int bstart[6];
};
__global__ __launch_bounds__(256) void k_transpose_all(TrJobs a) {
  const int b = blockIdx.x, tid = threadIdx.x;
  int j = 0;
  while (b >= a.bstart[j + 1]) ++j;
  const int base = (b - a.bstart[j]) * 1024;
  const int R = a.R[j], C = a.C[j], tot = R * C;
  const u16* in = a.src[j];
  u16* out = a.dst[j];
#pragma unroll
  for (int k = 0; k < 4; ++k) {
    int i = base + tid + k * 256;
    if (i < tot) { int r = i / C, c = i - r * C; out[c * R + r] = in[i]; }
  }
}

// ---------------- fused per-row 1/||x|| (3 jobs) ----------------
struct RnJobs {
  const u16* X[3];
  float* out[3];
  int rows[3];
  int bstart[4];
};
__global__ __launch_bounds__(256) void k_rownorm_all(RnJobs a) {
  const int b = blockIdx.x;
  int j = 0;
  while (b >= a.bstart[j + 1]) ++j;
  const int w = threadIdx.x >> 6, lane = threadIdx.x & 63;
  const int row = (b - a.bstart[j]) * 4 + w;
  if (row >= a.rows[j]) return;
  const u16* p = a.X[j] + (size_t)row * 256 + lane * 4;
  float s = 0.f;
#pragma unroll
  for (int i = 0; i < 4; ++i) { float v = bf2f(p[i]); s += v * v; }
  s = wred64(s);
  if (lane == 0) a.out[j][row] = rsqrtf(s);
}

// ---------------- start-vector MLP (1 block) -> ex0[128] ----------------
__global__ __launch_bounds__(256) void k_start(
    const u16* __restrict__ se,
    const u16* __restrict__ sw0, const u16* __restrict__ sb0,
    const u16* __restrict__ sw1, const u16* __restrict__ sb1,
    const u16* __restrict__ sw2, const u16* __restrict__ sb2,
    const u16* __restrict__ sw3, const u16* __restrict__ sb3,
    const u16* __restrict__ sw4, const u16* __restrict__ sb4,
    const u16* __restrict__ proj, float* __restrict__ ex0) {
  __shared__ float xa[256], xb[256], xc[256], red[256];
  const int tid = threadIdx.x;
  xa[tid] = bf2f(se[tid]);
  __syncthreads();
  float acc = bf2f(sb0[tid]);
  for (int k = 0; k < 256; ++k) acc += xa[k] * bf2f(sw0[k * 256 + tid]);
  xb[tid] = acc;
  __syncthreads();
  acc = bf2f(sb1[tid]);
  for (int k = 0; k < 256; ++k) acc += xb[k] * bf2f(sw1[k * 256 + tid]);
  xc[tid] = fmaxf(acc, 0.f);
  __syncthreads();
  acc = bf2f(sb2[tid]);
  for (int k = 0; k < 256; ++k) acc += xc[k] * bf2f(sw2[k * 256 + tid]);
  xa[tid] = fmaxf(acc, 0.f) + xb[tid];
  __syncthreads();
  acc = bf2f(sb3[tid]);
  for (int k = 0; k < 256; ++k) acc += xa[k] * bf2f(sw3[k * 256 + tid]);
  xc[tid] = fmaxf(acc, 0.f);
  __syncthreads();
  acc = bf2f(sb4[tid]);
  for (int k = 0; k < 256; ++k) acc += xc[k] * bf2f(sw4[k * 256 + tid]);
  xb[tid] = fmaxf(acc, 0.f) + xa[tid];
  __syncthreads();
  red[tid] = xb[tid] * xb[tid];
  __syncthreads();
  for (int s = 128; s > 0; s >>= 1) {
    if (tid < s) red[tid] += red[tid + s];
    __syncthreads();
  }
  const float rs = rsqrtf(red[0]);
  xa[tid] = xb[tid] * rs;
  __syncthreads();
  if (tid < 128) {
    float a = 0.f;
    for (int k = 0; k < 256; ++k) a += xa[k] * bf2f(proj[k * 128 + tid]);
    ex0[tid] = expf(a);
  }
}

// ---------------- preterminal MLP + fused rs_ft ----------------
__global__ __launch_bounds__(256) void k_mlp(
    const u16* __restrict__ X0,
    const u16* __restrict__ w1T, const u16* __restrict__ b1,
    const u16* __restrict__ w2T, const u16* __restrict__ b2,
    const u16* __restrict__ w3T, const u16* __restrict__ b3,
    const u16* __restrict__ w4T, const u16* __restrict__ b4,
    u16* __restrict__ FT, float* __restrict__ rs_ft) {
  __shared__ __align__(16) u16 Y[2][64][264];
  const int tid = threadIdx.x, lane = tid & 63, w = tid >> 6;
  const int m16 = lane & 15, kg = lane >> 4;
  const int rbl = w * 16;
  const int rbg = blockIdx.x * 64 + rbl;
  const floatx4 z4 = {0.f, 0.f, 0.f, 0.f};
  floatx4 acc[16];

#pragma unroll
  for (int ct = 0; ct < 16; ++ct) acc[ct] = z4;
  for (int k0 = 0; k0 < 256; k0 += 32) {
    bf16x8 a = ld8(X0 + (size_t)(rbg + m16) * 256 + k0 + kg * 8);
#pragma unroll
    for (int ct = 0; ct < 16; ++ct)
      acc[ct] = MFMA16(a, ld8(w1T + (ct * 16 + m16) * 256 + k0 + kg * 8), acc[ct]);
  }
#pragma unroll
  for (int ct = 0; ct < 16; ++ct) {
    const int col = ct * 16 + m16;
    const float bv = bf2f(b1[col]);
#pragma unroll
    for (int r = 0; r < 4; ++r)
      Y[0][rbl + kg * 4 + r][col] = f2bf(fmaxf(acc[ct][r] + bv, 0.f));
  }
  __syncthreads();
#pragma unroll
  for (int ct = 0; ct < 16; ++ct) acc[ct] = z4;
  for (int k0 = 0; k0 < 256; k0 += 32) {
    bf16x8 a = *(const bf16x8*)(&Y[0][rbl + m16][k0 + kg * 8]);
#pragma unroll
    for (int ct = 0; ct < 16; ++ct)
      acc[ct] = MFMA16(a, ld8(w2T + (ct * 16 + m16) * 256 + k0 + kg * 8), acc[ct]);
  }
#pragma unroll
  for (int ct = 0; ct < 16; ++ct) {
    const int col = ct * 16 + m16;
    const float bv = bf2f(b2[col]);
#pragma unroll
    for (int r = 0; r < 4; ++r) {
      const int gr = rbg + kg * 4 + r;
      float v = fmaxf(acc[ct][r] + bv, 0.f) + bf2f(X0[(size_t)gr * 256 + col]);
      Y[1][rbl + kg * 4 + r][col] = f2bf(v);
    }
  }
  __syncthreads();
#pragma unroll
  for (int ct = 0; ct < 16; ++ct) acc[ct] = z4;
  for (int k0 = 0; k0 < 256; k0 += 32) {
    bf16x8 a = *(const bf16x8*)(&Y[1][rbl + m16][k0 + kg * 8]);
#pragma unroll
    for (int ct = 0; ct < 16; ++ct)
      acc[ct] = MFMA16(a, ld8(w3T + (ct * 16 + m16) * 256 + k0 + kg * 8), acc[ct]);
  }
#pragma unroll
  for (int ct = 0; ct < 16; ++ct) {
    const int col = ct * 16 + m16;
    const float bv = bf2f(b3[col]);
#pragma unroll
    for (int r = 0; r < 4; ++r)
      Y[0][rbl + kg * 4 + r][col] = f2bf(fmaxf(acc[ct][r] + bv, 0.f));
  }
  __syncthreads();
#pragma unroll
  for (int ct = 0; ct < 16; ++ct) acc[ct] = z4;
  for (int k0 = 0; k0 < 256; k0 += 32) {
    bf16x8 a = *(const bf16x8*)(&Y[0][rbl + m16][k0 + kg * 8]);
#pragma unroll
    for (int ct = 0; ct < 16; ++ct)
      acc[ct] = MFMA16(a, ld8(w4T + (ct * 16 + m16) * 256 + k0 + kg * 8), acc[ct]);
  }
  float ssq[4] = {0.f, 0.f, 0.f, 0.f};
#pragma unroll
  for (int ct = 0; ct < 16; ++ct) {
    const int col = ct * 16 + m16;
    const float bv = bf2f(b4[col]);
#pragma unroll
    for (int r = 0; r < 4; ++r) {
      const int rl = rbl + kg * 4 + r;
      float v = fmaxf(acc[ct][r] + bv, 0.f) + bf2f(Y[1][rl][col]);
      ssq[r] += v * v;
      FT[(size_t)(rbg + kg * 4 + r) * 256 + col] = f2bf(v);
    }
  }
  // fused row-norm: reduce ssq across the 16 lanes sharing kg
#pragma unroll
  for (int r = 0; r < 4; ++r) {
    float s = ssq[r];
#pragma unroll
    for (int mk = 1; mk < 16; mk <<= 1) s += __shfl_xor(s, mk, 64);
    if (m16 == 0) rs_ft[rbg + kg * 4 + r] = rsqrtf(s);
  }
}

// ---------------- fused features mega-kernel ----------------
__device__ void feat_body(const u16* __restrict__ X, const float* __restrict__ rscale,
                          const u16* __restrict__ PT, u16* __restrict__ OUT, int blk,
                          float* __restrict__ SBN) {
  __shared__ float cred[128];
  const int tid = threadIdx.x, lane = tid & 63, w = tid >> 6;
  const int m16 = lane & 15, kg = lane >> 4;
  const int rb = blk * 64 + w * 16;
  if (SBN) {
    if (tid < 128) cred[tid] = 0.f;
    __syncthreads();
  }
  const floatx4 z4 = {0.f, 0.f, 0.f, 0.f};
  floatx4 acc[8];
#pragma unroll
  for (int ct = 0; ct < 8; ++ct) acc[ct] = z4;
  for (int k0 = 0; k0 < 256; k0 += 32) {
    bf16x8 a = ld8(X + (size_t)(rb + m16) * 256 + k0 + kg * 8);
#pragma unroll
    for (int ct = 0; ct < 8; ++ct)
      acc[ct] = MFMA16(a, ld8(PT + (ct * 16 + m16) * 256 + k0 + kg * 8), acc[ct]);
  }
  float rs[4];
#pragma unroll
  for (int r = 0; r < 4; ++r) rs[r] = rscale[rb + kg * 4 + r];
#pragma unroll
  for (int ct = 0; ct < 8; ++ct) {
    float s = 0.f;
#pragma unroll
    for (int r = 0; r < 4; ++r) {
      float v = expf(acc[ct][r] * rs[r]);
      s += v;
      OUT[(size_t)(rb + kg * 4 + r) * 128 + ct * 16 + m16] = f2bf(v);
    }
    if (SBN) atomicAdd(&cred[ct * 16 + m16], s);
  }
  if (SBN) {
    __syncthreads();
    if (tid < 128) atomicAdd(&SBN[tid], cred[tid]);
  }
}

__device__ void gather_body(const int* __restrict__ text, const u16* __restrict__ TE,
                            const float* __restrict__ rs_term, const u16* __restrict__ PT,
                            u16* __restrict__ Btok, int blk) {
  const int tid = threadIdx.x, lane = tid & 63, w = tid >> 6;
  const int m16 = lane & 15, kg = lane >> 4;
  const int rb = blk * 64 + w * 16;
  const int ia = rb + m16;
  const int tok_a = text[(ia & 15) * 256 + (ia >> 4)];
  const floatx4 z4 = {0.f, 0.f, 0.f, 0.f};
  floatx4 acc[8];
#pragma unroll
  for (int ct = 0; ct < 8; ++ct) acc[ct] = z4;
  for (int k0 = 0; k0 < 256; k0 += 32) {
    bf16x8 a = ld8(TE + (size_t)tok_a * 256 + k0 + kg * 8);
#pragma unroll
    for (int ct = 0; ct < 8; ++ct)
      acc[ct] = MFMA16(a, ld8(PT + (ct * 16 + m16) * 256 + k0 + kg * 8), acc[ct]);
  }
  float rs[4];
#pragma unroll
  for (int r = 0; r < 4; ++r) {
    const int io = rb + kg * 4 + r;
    rs[r] = rs_term[text[(io & 15) * 256 + (io >> 4)]];
  }
#pragma unroll
  for (int ct = 0; ct < 8; ++ct)
#pragma unroll
    for (int r = 0; r < 4; ++r)
      Btok[(size_t)(rb + kg * 4 + r) * 128 + ct * 16 + m16] = f2bf(expf(acc[ct][r] * rs[r]));
}

__device__ void colsum_body(const u16* __restrict__ X, const float* __restrict__ rscale,
                            const u16* __restrict__ PT, float* __restrict__ part, int blk) {
  __shared__ float cred2[128];
  const int tid = threadIdx.x, lane = tid & 63, w = tid >> 6;
  const int m16 = lane & 15, kg = lane >> 4;
  const int rb = blk * 64 + w * 16;
  if (tid < 128) cred2[tid] = 0.f;
  __syncthreads();
  const floatx4 z4 = {0.f, 0.f, 0.f, 0.f};
  floatx4 acc[8];
#pragma unroll
  for (int ct = 0; ct < 8; ++ct) acc[ct] = z4;
  for (int k0 = 0; k0 < 256; k0 += 32) {
    bf16x8 a = ld8(X + (size_t)(rb + m16) * 256 + k0 + kg * 8);
#pragma unroll
    for (int ct = 0; ct < 8; ++ct)
      acc[ct] = MFMA16(a, ld8(PT + (ct * 16 + m16) * 256 + k0 + kg * 8), acc[ct]);
  }
  float rs[4];
#pragma unroll
  for (int r = 0; r < 4; ++r) rs[r] = rscale[rb + kg * 4 + r];
#pragma unroll
  for (int ct = 0; ct < 8; ++ct) {
    float s = 0.f;
#pragma unroll
    for (int r = 0; r < 4; ++r) s += expf(acc[ct][r] * rs[r]);
    atomicAdd(&cred2[ct * 16 + m16], s);
  }
  __syncthreads();
  if (tid < 128) part[(size_t)blk * 128 + tid] = cred2[tid];
}

__global__ __launch_bounds__(256) void k_featall(
    const u16* __restrict__ c_state, const float* __restrict__ rs_state, u16* __restrict__ AxS,
    const u16* __restrict__ c_next, const float* __restrict__ rs_next, u16* __restrict__ ByN,
    float* __restrict__ SBN,
    const u16* __restrict__ ft, const float* __restrict__ rs_ft, u16* __restrict__ AxP,
    const int* __restrict__ text, const u16* __restrict__ c_term,
    const float* __restrict__ rs_term, u16* __restrict__ Btok,
    float* __restrict__ SBTpart, const u16* __restrict__ PT) {
  const int b = blockIdx.x;
  if (b < 64) feat_body(c_state, rs_state, PT, AxS, b, nullptr);
  else if (b < 128) feat_body(c_next, rs_next, PT, ByN, b - 64, SBN);
  else if (b < 192) feat_body(ft, rs_ft, PT, AxP, b - 128, nullptr);
  else if (b < 256) gather_body(text, c_term, rs_term, PT, Btok, b - 192);
  else colsum_body(c_term, rs_term, PT, SBTpart, b - 256);
}

__global__ void k_colred(const float* __restrict__ part, float* __restrict__ out, int nblk) {
  const int tid = threadIdx.x;
  if (tid < 128) {
    float s = 0.f;
    for (int b = 0; b < nblk; ++b) s += part[(size_t)b * 128 + tid];
    out[tid] = s;
  }
}

// ---------------- per-state scalars ----------------
__global__ __launch_bounds__(256) void k_vecdots(
    const u16* __restrict__ AxS, const u16* __restrict__ AxP, const u16* __restrict__ ByN,
    const float* __restrict__ SBN, const float* __restrict__ SBT, const float* __restrict__ ex0,
    float* __restrict__ recip_r, float* __restrict__ recip_den,
    float* __restrict__ start_raw) {
  const int w = threadIdx.x >> 6, lane = threadIdx.x & 63;
  const int c = blockIdx.x * 4 + w;
  const int d = lane * 2;
  float a0 = bf2f(AxS[(size_t)c * 128 + d]), a1 = bf2f(AxS[(size_t)c * 128 + d + 1]);
  float t = wred64(a0 * SBN[d] + a1 * SBN[d + 1]);
  float p0 = bf2f(AxP[(size_t)c * 128 + d]), p1 = bf2f(AxP[(size_t)c * 128 + d + 1]);
  float p = wred64(p0 * SBT[d] + p1 * SBT[d + 1]);
  float y0 = bf2f(ByN[(size_t)c * 128 + d]), y1 = bf2f(ByN[(size_t)c * 128 + d + 1]);
  float s = wred64(y0 * ex0[d] + y1 * ex0[d + 1]);
  if (lane == 0) {
    recip_r[c] = 1.0f / t;
    recip_den[c] = 1.0f / p;
    start_raw[c] = s;
  }
}

// ---------------- AxS2T[d][c] = AxS[c][d] * recip_r[c] ----------------
__global__ void k_foldT(const u16* __restrict__ AxS, const float* __restrict__ recip_r,
                        u16* __restrict__ AxS2T) {
  int i = blockIdx.x * 256 + threadIdx.x;
  if (i >= 128 * 4096) return;
  int d = i >> 12, c = i & 4095;
  AxS2T[i] = f2bf(bf2f(AxS[(size_t)c * 128 + d]) * recip_r[c]);
}

// ---------------- EMr blocked layout: EMr[(cb*256+t)*4096 + n*256 + cl] ----------------
__global__ __launch_bounds__(256) void k_pair(const u16* __restrict__ A, const u16* __restrict__ B,
                                              const float* __restrict__ cscale,
                                              u16* __restrict__ EMr) {
  const int tid = threadIdx.x, lane = tid & 63, w = tid >> 6;
  const int m16 = lane & 15, kg = lane >> 4;
  const int mb = blockIdx.y * 128 + w * 32;
  const int nb = blockIdx.x * 128;
  const floatx4 z4 = {0.f, 0.f, 0.f, 0.f};
  floatx4 acc[2][8];
#pragma unroll
  for (int rt = 0; rt < 2; ++rt)
#pragma unroll
    for (int ct = 0; ct < 8; ++ct) acc[rt][ct] = z4;
  for (int k0 = 0; k0 < 128; k0 += 32) {
    bf16x8 a0 = ld8(A + (size_t)(mb + m16) * 128 + k0 + kg * 8);
    bf16x8 a1 = ld8(A + (size_t)(mb + 16 + m16) * 128 + k0 + kg * 8);
#pragma unroll
    for (int ct = 0; ct < 8; ++ct) {
      bf16x8 bb = ld8(B + (size_t)(nb + ct * 16 + m16) * 128 + k0 + kg * 8);
      acc[0][ct] = MFMA16(a0, bb, acc[0][ct]);
      acc[1][ct] = MFMA16(a1, bb, acc[1][ct]);
    }
  }
  float cs[8];
#pragma unroll
  for (int ct = 0; ct < 8; ++ct) cs[ct] = cscale[nb + ct * 16 + m16];
#pragma unroll
  for (int rt = 0; rt < 2; ++rt)
#pragma unroll
    for (int ct = 0; ct < 8; ++ct)
#pragma unroll
      for (int r = 0; r < 4; ++r) {
        const int row = mb + rt * 16 + kg * 4 + r;  // nt
        const int col = nb + ct * 16 + m16;         // c
        const int t = row >> 4, n = row & 15;
        const size_t idx = ((size_t)(col >> 8) * 256 + t) * 4096 + n * 256 + (col & 255);
        EMr[idx] = f2bf(acc[rt][ct][r] * cs[ct]);
      }
}

// ---------------- persistent 16-block scan, per-block flag barrier ----------------
__global__ __launch_bounds__(256) void k_scan(
    const u16* __restrict__ EMr, const u16* __restrict__ ByN, const u16* __restrict__ AxS2T,
    const float* __restrict__ start_raw,
    float* __restrict__ Vacc, float* __restrict__ SaccP, u32* __restrict__ flags,
    float* __restrict__ ssum_s, const int* __restrict__ flag, u16* __restrict__ outp) {
  __shared__ __align__(16) u16 ByNs[256][132];
  __shared__ __align__(16) u16 AxS2s[128][260];
  __shared__ __align__(16) u16 ush[16][264];
  __shared__ __align__(16) u16 vsh[16][136];
  __shared__ __align__(16) u16 emt[16][264];
  __shared__ float red2[256];
  __shared__ float recipS[16];
  __shared__ float finred[16];
  __shared__ int timeout_sh;
  const int tid = threadIdx.x, lane = tid & 63, w = tid >> 6;
  const int m16 = lane & 15, kg = lane >> 4;
  const int b = blockIdx.x, cb = b * 256;
  const floatx4 z4 = {0.f, 0.f, 0.f, 0.f};
  float evreg = 0.f;

  if (tid == 0) timeout_sh = 0;
  for (int i = tid; i < 4096; i += 256) {
    const int r = i >> 4, c8 = (i & 15) * 8;
    *(uint4*)(&ByNs[r][c8]) = *(const uint4*)(ByN + (size_t)(cb + r) * 128 + c8);
  }
  for (int i = tid; i < 4096; i += 256) {
    const int e = i >> 5, c8 = (i & 31) * 8;
    *(uint4*)(&AxS2s[e][c8]) = *(const uint4*)(AxS2T + (size_t)e * 4096 + cb + c8);
  }
  // ssum partial (once)
  {
    float s = wred64(start_raw[cb + tid]);
    if (lane == 0) atomicAdd(ssum_s, s);
  }
  // t=0 EM tile -> LDS
  {
    const u16* g0 = EMr + (size_t)(b * 256) * 4096;
    const int c0 = tid, c1 = tid + 256;
    uint4 e0 = *(const uint4*)(g0 + c0 * 8), e1 = *(const uint4*)(g0 + c1 * 8);
    *(uint4*)(&emt[c0 >> 5][(c0 & 31) * 8]) = e0;
    *(uint4*)(&emt[c1 >> 5][(c1 & 31) * 8]) = e1;
  }
  __syncthreads();
  // t=0: u0 = start_raw * EM0
  {
    const int n0 = tid >> 4, cg0 = tid & 15;
    float s0 = 0.f;
#pragma unroll
    for (int j = 0; j < 16; ++j) {
      const int c = cg0 * 16 + j;
      float u = start_raw[cb + c] * bf2f(emt[n0][c]);
      ush[n0][c] = f2bf(u);
      s0 += u;
    }
    red2[tid] = s0;
  }
  __syncthreads();
  if (tid < 16) {
    float S = 0.f;
#pragma unroll
    for (int j = 0; j < 16; ++j) S += red2[tid * 16 + j];
    atomicAdd(&SaccP[tid * 16], S);
  }
#pragma unroll
  for (int ct2i = 0; ct2i < 2; ++ct2i) {
    const int ct2 = (ct2i + b) & 1;
    const int ct = w * 2 + ct2;
    floatx4 acc = z4;
#pragma unroll
    for (int k0 = 0; k0 < 256; k0 += 32)
      acc = MFMA16(*(const bf16x8*)(&ush[m16][k0 + kg * 8]),
                   *(const bf16x8*)(&AxS2s[ct * 16 + m16][k0 + kg * 8]), acc);
#pragma unroll
    for (int ri = 0; ri < 4; ++ri) {
      const int r = (ri + b) & 3;
      atomicAdd(&Vacc[(size_t)(kg * 4 + r) * 128 + ct * 16 + m16], acc[r]);
    }
  }
  __threadfence();
  __syncthreads();
  if (tid == 0)
    __hip_atomic_store(&flags[b], 1u, __ATOMIC_RELEASE, __HIP_MEMORY_SCOPE_AGENT);

  for (int t = 1; t < 256; ++t) {
    // prefetch EM tile (regs) before the spin
    const u16* g = EMr + (size_t)(b * 256 + t) * 4096;
    uint4 e0 = *(const uint4*)(g + tid * 8);
    uint4 e1 = *(const uint4*)(g + (tid + 256) * 8);
    // barrier: 16 lanes poll 16 per-block flags in parallel
    if (w == 0) {
      long it = 0;
      int mydone = (lane >= 16);
      while (!__all(mydone)) {
        if (lane < 16 && !mydone)
          mydone = (__hip_atomic_load(&flags[(t - 1) * 16 + lane], __ATOMIC_ACQUIRE,
                                      __HIP_MEMORY_SCOPE_AGENT) == (u32)t);
        __builtin_amdgcn_s_sleep(1);
        if (++it > 30000000L) { if (lane == 0) timeout_sh = 1; break; }
      }
    }
    __syncthreads();
    if (timeout_sh) break;
    if (tid < 16) {
      float S = __hip_atomic_load(&SaccP[(size_t)(t - 1) * 256 + tid * 16], __ATOMIC_RELAXED,
                                  __HIP_MEMORY_SCOPE_AGENT);
      recipS[tid] = 1.0f / S;
      if (b == 0) evreg += logf(S);
    }
    float vv[8];
    const int n1 = tid >> 4, d8 = (tid & 15) * 8;
    {
      const float* vp = Vacc + (size_t)((t - 1) * 16 + n1) * 128 + d8;
#pragma unroll
      for (int j = 0; j < 8; ++j)
        vv[j] = __hip_atomic_load(vp + j, __ATOMIC_RELAXED, __HIP_MEMORY_SCOPE_AGENT);
    }
    // write EM tile to LDS
    *(uint4*)(&emt[tid >> 5][(tid & 31) * 8]) = e0;
    *(uint4*)(&emt[(tid + 256) >> 5][((tid + 256) & 31) * 8]) = e1;
    __syncthreads();
    {
      const float rS = recipS[n1];
      u16 tmp[8];
#pragma unroll
      for (int j = 0; j < 8; ++j) tmp[j] = f2bf(vv[j] * rS);
      *(uint4*)(&vsh[n1][d8]) = *(uint4*)tmp;
    }
    __syncthreads();
    // expand
#pragma unroll
    for (int ct2 = 0; ct2 < 4; ++ct2) {
      const int ct = w * 4 + ct2;
      floatx4 acc = z4;
#pragma unroll
      for (int k0 = 0; k0 < 128; k0 += 32)
        acc = MFMA16(*(const bf16x8*)(&vsh[m16][k0 + kg * 8]),
                     *(const bf16x8*)(&ByNs[ct * 16 + m16][k0 + kg * 8]), acc);
#pragma unroll
      for (int r = 0; r < 4; ++r)
        ush[kg * 4 + r][ct * 16 + m16] =
            f2bf(acc[r] * bf2f(emt[kg * 4 + r][ct * 16 + m16]));
    }
    __syncthreads();
    // S partial
    {
      const int n = tid >> 4, jg = tid & 15;
      float s = 0.f;
#pragma unroll
      for (int k = 0; k < 16; ++k) s += bf2f(ush[n][jg * 16 + k]);
      red2[tid] = s;
    }
    __syncthreads();
    if (tid < 16) {
      float S = 0.f;
#pragma unroll
      for (int j = 0; j < 16; ++j) S += red2[tid * 16 + j];
      atomicAdd(&SaccP[(size_t)t * 256 + tid * 16], S);
    }
    // contract (staggered publish)
#pragma unroll
    for (int ct2i = 0; ct2i < 2; ++ct2i) {
      const int ct2 = (ct2i + b) & 1;
      const int ct = w * 2 + ct2;
      floatx4 acc = z4;
#pragma unroll
      for (int k0 = 0; k0 < 256; k0 += 32)
        acc = MFMA16(*(const bf16x8*)(&ush[m16][k0 + kg * 8]),
                     *(const bf16x8*)(&AxS2s[ct * 16 + m16][k0 + kg * 8]), acc);
#pragma unroll
      for (int ri = 0; ri < 4; ++ri) {
        const int r = (ri + b) & 3;
        atomicAdd(&Vacc[(size_t)(t * 16 + kg * 4 + r) * 128 + ct * 16 + m16], acc[r]);
      }
    }
    __threadfence();
    __syncthreads();
    if (tid == 0)
      __hip_atomic_store(&flags[t * 16 + b], (u32)(t + 1), __ATOMIC_RELEASE,
                         __HIP_MEMORY_SCOPE_AGENT);
  }

  if (b == 0) {
    if (w == 0 && !timeout_sh) {
      long it = 0;
      int mydone = (lane >= 16);
      while (!__all(mydone)) {
        if (lane < 16 && !mydone)
          mydone = (__hip_atomic_load(&flags[255 * 16 + lane], __ATOMIC_ACQUIRE,
                                      __HIP_MEMORY_SCOPE_AGENT) == 256u);
        __builtin_amdgcn_s_sleep(1);
        if (++it > 30000000L) { if (lane == 0) timeout_sh = 1; break; }
      }
    }
    __syncthreads();
    if (tid < 16) {
      float S = __hip_atomic_load(&SaccP[(size_t)255 * 256 + tid * 16], __ATOMIC_RELAXED,
                                  __HIP_MEMORY_SCOPE_AGENT);
      finred[tid] = evreg + logf(S);
    }
    __syncthreads();
    if (tid == 0) {
      float ev = 0.f;
      for (int i = 0; i < 16; ++i) ev += finred[i];
      ev -= 16.0f * logf(*ssum_s);
      if (timeout_sh) ev = -66666.0f;
      store_final(outp, ev, *flag);
    }
  }
}

extern "C" void kernel_launch(void* const* d_in, const int* in_sizes, int n_in,
                              void* d_out, int out_size, void* d_ws, size_t ws_size,
                              hipStream_t stream) {
  (void)out_size;
  u16* outp = (u16*)d_out;
  if (n_in != 26 || in_sizes[25] != 128 * 256) {
    k_sentinel<<<1, 1, 0, stream>>>(outp, 5000.0f + (float)n_in);
    return;
  }
  const int* text = (const int*)d_in[0];

  char* base = (char*)d_ws;
  size_t off = 0;
  auto take = [&](size_t bytes) -> char* {
    char* p = base + off;
    off = (off + bytes + 255) & ~(size_t)255;
    return p;
  };
  int* flag = (int*)take(256);
  u16* c_se   = (u16*)take(256 * 2);
  u16* c_w[18];
  for (int i = 0; i < 18; ++i) c_w[i] = (u16*)take(((i & 1) ? 256 : 65536) * 2);
  u16* c_state = (u16*)take((size_t)1048576 * 2);
  u16* c_next  = (u16*)take((size_t)1048576 * 2);
  u16* c_pre   = (u16*)take((size_t)1048576 * 2);
  u16* c_term  = (u16*)take((size_t)8192000 * 2);
  u16* c_proj  = (u16*)take((size_t)32768 * 2);
  u16* projT  = (u16*)take(128 * 256 * 2);
  u16* twT1   = (u16*)take(65536 * 2);
  u16* twT2   = (u16*)take(65536 * 2);
  u16* twT3   = (u16*)take(65536 * 2);
  u16* twT4   = (u16*)take(65536 * 2);
  u16* ft     = (u16*)take((size_t)4096 * 256 * 2);
  float* rs_state = (float*)take(4096 * 4);
  float* rs_next  = (float*)take(4096 * 4);
  float* rs_ft    = (float*)take(4096 * 4);
  float* rs_term  = (float*)take(32000 * 4);
  u16* AxS    = (u16*)take((size_t)4096 * 128 * 2);
  u16* ByN    = (u16*)take((size_t)4096 * 128 * 2);
  u16* AxP    = (u16*)take((size_t)4096 * 128 * 2);
  u16* Btok   = (u16*)take((size_t)4096 * 128 * 2);
  u16* AxS2T  = (u16*)take((size_t)128 * 4096 * 2);
  u16* EMr    = (u16*)take((size_t)4096 * 4096 * 2);
  float* SBTpart = (float*)take(500 * 128 * 4);
  float* recip_r   = (float*)take(4096 * 4);
  float* recip_den = (float*)take(4096 * 4);
  float* start_raw = (float*)take(4096 * 4);
  float* ex0       = (float*)take(128 * 4);
  // zeroed region: zreg (SBN|SBT) + barrier (flags | SaccP | Vacc | ssum)
  float* zreg = (float*)take(2048);
  float* SBN = zreg, *SBT = zreg + 128;
  const size_t barr_sz = 16384 + 262144 + (size_t)2097152 + 256;
  char* barr = take(barr_sz);
  u32* flags  = (u32*)barr;                       // [256][16]
  float* SaccP = (float*)(barr + 16384);          // [256][16][16]
  float* Vacc  = (float*)(barr + 16384 + 262144); // [256][16][128]
  float* ssum_s = (float*)(barr + 16384 + 262144 + 2097152);

  const float ws_mb = (float)(ws_size >> 20) > 900.f ? 900.f : (float)(ws_size >> 20);
  if (off > ws_size) {
    k_sentinel<<<1, 1, 0, stream>>>(outp, 1000.0f + ws_mb);
    return;
  }

  k_detect<<<1, 64, 0, stream>>>((const u32*)d_in[25], flag);
  k_sentinel<<<1, 1, 0, stream>>>(outp, -7777.0f);  // breadcrumb
  hipMemsetAsync(zreg, 0, 2048 + barr_sz, stream);

  // fused convert: 24 jobs
  CvtJobs cj;
  int cb_ = 0, cjn = 0;
  auto addcvt = [&](const void* s, u16* d, int n) {
    cj.src[cjn] = s; cj.dst[cjn] = d; cj.n[cjn] = n;
    cj.bstart[cjn] = cb_; cb_ += (n + 4095) / 4096; ++cjn;
  };
  addcvt(d_in[2], c_se, 256);
  for (int i = 0; i < 18; ++i) addcvt(d_in[3 + i], c_w[i], (i & 1) ? 256 : 65536);
  addcvt(d_in[21], c_state, 1048576);
  addcvt(d_in[22], c_next, 1048576);
  addcvt(d_in[23], c_pre, 1048576);
  addcvt(d_in[24], c_term, 8192000);
  addcvt(d_in[25], c_proj, 32768);
  cj.bstart[24] = cb_;
  k_cvt_all<<<cb_, 256, 0, stream>>>(cj, flag);

  // fused transposes: 5 jobs
  TrJobs tj;
  tj.src[0] = c_proj; tj.dst[0] = projT; tj.R[0] = 256; tj.C[0] = 128;
  tj.src[1] = c_w[10]; tj.dst[1] = twT1; tj.R[1] = 256; tj.C[1] = 256;
  tj.src[2] = c_w[12]; tj.dst[2] = twT2; tj.R[2] = 256; tj.C[2] = 256;
  tj.src[3] = c_w[14]; tj.dst[3] = twT3; tj.R[3] = 256; tj.C[3] = 256;
  tj.src[4] = c_w[16]; tj.dst[4] = twT4; tj.R[4] = 256; tj.C[4] = 256;
  int tb = 0;
  for (int j = 0; j < 5; ++j) { tj.bstart[j] = tb; tb += (tj.R[j] * tj.C[j]) / 1024; }
  tj.bstart[5] = tb;
  k_transpose_all<<<tb, 256, 0, stream>>>(tj);

  // fused rownorm: state, next, term
  RnJobs rj;
  rj.X[0] = c_state; rj.out[0] = rs_state; rj.rows[0] = 4096;
  rj.X[1] = c_next;  rj.out[1] = rs_next;  rj.rows[1] = 4096;
  rj.X[2] = c_term;  rj.out[2] = rs_term;  rj.rows[2] = 32000;
  rj.bstart[0] = 0; rj.bstart[1] = 1024; rj.bstart[2] = 2048; rj.bstart[3] = 10048;
  k_rownorm_all<<<10048, 256, 0, stream>>>(rj);

  k_start<<<1, 256, 0, stream>>>(c_se, c_w[0], c_w[1], c_w[2], c_w[3], c_w[4], c_w[5],
                                 c_w[6], c_w[7], c_w[8], c_w[9], c_proj, ex0);
  k_mlp<<<64, 256, 0, stream>>>(c_pre, twT1, c_w[11], twT2, c_w[13], twT3, c_w[15],
                                twT4, c_w[17], ft, rs_ft);
  k_featall<<<756, 256, 0, stream>>>(c_state, rs_state, AxS, c_next, rs_next, ByN, SBN,
                                     ft, rs_ft, AxP, text, c_term, rs_term, Btok,
                                     SBTpart, projT);
  k_colred<<<1, 256, 0, stream>>>(SBTpart, SBT, 500);
  k_vecdots<<<1024, 256, 0, stream>>>(AxS, AxP, ByN, SBN, SBT, ex0, recip_r, recip_den,
                                      start_raw);
  k_foldT<<<2048, 256, 0, stream>>>(AxS, recip_r, AxS2T);
  k_pair<<<dim3(32, 32), 256, 0, stream>>>(Btok, AxP, recip_den, EMr);

  k_scan<<<16, 256, 0, stream>>>(EMr, ByN, AxS2T, start_raw, Vacc, SaccP, flags, ssum_s,
                                 flag, outp);
}